// Round 1
// baseline (5745.920 us; speedup 1.0000x reference)
//
#include <hip/hip_runtime.h>

#define N_NODES 100000
#define NE      1600000
#define DIM     128

// ws layout (float elements)
#define CNT_OFF 0
#define AGG_OFF 102400                       // cnt padded/aligned
#define H_OFF   (AGG_OFF + N_NODES * DIM)    // 12,902,400
// total ws floats = H_OFF + N*DIM = 25,702,400  (~103 MB)

// ---------------- degree count ----------------
__global__ void k_count(const int* __restrict__ dst, float* __restrict__ cnt) {
    int e = blockIdx.x * 256 + threadIdx.x;
    if (e < NE) atomicAdd(&cnt[dst[e]], 1.0f);
}

// ---------------- scatter-add of features ----------------
// one edge handled by 32 threads, 4 floats each (float4 load, 4 atomics)
__global__ void k_scatter(const int* __restrict__ src, const int* __restrict__ dst,
                          const float* __restrict__ feat, float* __restrict__ agg) {
    long tid = (long)blockIdx.x * 256 + threadIdx.x;
    int e = (int)(tid >> 5);
    if (e >= NE) return;
    int f = ((int)tid & 31) * 4;
    int s = src[e], d = dst[e];
    float4 v = *reinterpret_cast<const float4*>(&feat[(long)s * DIM + f]);
    float* base = &agg[(long)d * DIM + f];
    atomicAdd(base + 0, v.x);
    atomicAdd(base + 1, v.y);
    atomicAdd(base + 2, v.z);
    atomicAdd(base + 3, v.w);
}

// ---------------- fused SAGE linear layer ----------------
// out[n][o] = (agg[n]/max(cnt,1)) . Wl[o][:] + xin[n] . Wr[o][:] + bias[o]  (opt relu)
// Treated as GEMM: A[N x 256] (=[mean|x]) times B[256 x 128] (B[k][o]=Wcat[o][k]).
// Block: 256 threads, tile M=64 nodes x 128 outs, K in 8 chunks of 32.
// Thread (ty,tx) = (tid>>4, tid&15): rows ty*4..+4, cols tx*8..+8 -> 4x8 acc.
template <bool RELU>
__global__ __launch_bounds__(256) void k_layer(
    const float* __restrict__ agg, const float* __restrict__ cnt,
    const float* __restrict__ xin,
    const float* __restrict__ Wl, const float* __restrict__ Wr,
    const float* __restrict__ bias, float* __restrict__ out)
{
    __shared__ float As[32][72];    // As[kk][row]  (transposed A tile)
    __shared__ float Bs[32][132];   // Bs[kk][o]

    const int tid = threadIdx.x;
    const int ty = tid >> 4, tx = tid & 15;
    const int n0 = blockIdx.x * 64;

    float acc[4][8];
#pragma unroll
    for (int i = 0; i < 4; ++i)
#pragma unroll
        for (int j = 0; j < 8; ++j) acc[i][j] = 0.0f;

    // staging roles
    const int ar = tid >> 2;            // 0..63 : A row
    const int akk0 = (tid & 3) * 8;     // 0,8,16,24
    const int bo = tid >> 1;            // 0..127 : B output row
    const int bkk0 = (tid & 1) * 16;    // 0,16

    for (int kb = 0; kb < 8; ++kb) {
        // ---- stage A (64 rows x 32 k), transposed into As[kk][row] ----
        {
            int n = n0 + ar;
            float vals[8];
            if (n < N_NODES) {
                if (kb < 4) {
                    int kg = kb * 32 + akk0;
                    float rinv = 1.0f / fmaxf(cnt[n], 1.0f);
                    float4 v0 = *reinterpret_cast<const float4*>(&agg[(long)n * DIM + kg]);
                    float4 v1 = *reinterpret_cast<const float4*>(&agg[(long)n * DIM + kg + 4]);
                    vals[0] = v0.x * rinv; vals[1] = v0.y * rinv; vals[2] = v0.z * rinv; vals[3] = v0.w * rinv;
                    vals[4] = v1.x * rinv; vals[5] = v1.y * rinv; vals[6] = v1.z * rinv; vals[7] = v1.w * rinv;
                } else {
                    int kg = (kb - 4) * 32 + akk0;
                    float4 v0 = *reinterpret_cast<const float4*>(&xin[(long)n * DIM + kg]);
                    float4 v1 = *reinterpret_cast<const float4*>(&xin[(long)n * DIM + kg + 4]);
                    vals[0] = v0.x; vals[1] = v0.y; vals[2] = v0.z; vals[3] = v0.w;
                    vals[4] = v1.x; vals[5] = v1.y; vals[6] = v1.z; vals[7] = v1.w;
                }
            } else {
#pragma unroll
                for (int j = 0; j < 8; ++j) vals[j] = 0.0f;
            }
#pragma unroll
            for (int j = 0; j < 8; ++j) As[akk0 + j][ar] = vals[j];
        }
        // ---- stage B (32 k x 128 o): Bs[kk][o] = W[o][kg+kk] ----
        {
            const float* Wp = (kb < 4) ? Wl : Wr;
            int kg = (kb & 3) * 32 + bkk0;
            const float* wrow = &Wp[(long)bo * DIM + kg];
#pragma unroll
            for (int j = 0; j < 16; j += 4) {
                float4 w = *reinterpret_cast<const float4*>(&wrow[j]);
                Bs[bkk0 + j + 0][bo] = w.x;
                Bs[bkk0 + j + 1][bo] = w.y;
                Bs[bkk0 + j + 2][bo] = w.z;
                Bs[bkk0 + j + 3][bo] = w.w;
            }
        }
        __syncthreads();

        // ---- inner product over 32 k ----
#pragma unroll
        for (int kk = 0; kk < 32; ++kk) {
            float4 a = *reinterpret_cast<const float4*>(&As[kk][ty * 4]);
            float4 b0 = *reinterpret_cast<const float4*>(&Bs[kk][tx * 8]);
            float4 b1 = *reinterpret_cast<const float4*>(&Bs[kk][tx * 8 + 4]);
            float av[4] = {a.x, a.y, a.z, a.w};
            float bv[8] = {b0.x, b0.y, b0.z, b0.w, b1.x, b1.y, b1.z, b1.w};
#pragma unroll
            for (int i = 0; i < 4; ++i)
#pragma unroll
                for (int j = 0; j < 8; ++j)
                    acc[i][j] = fmaf(av[i], bv[j], acc[i][j]);
        }
        __syncthreads();
    }

    // ---- epilogue: bias (+relu), store ----
    float bv[8];
#pragma unroll
    for (int j = 0; j < 8; ++j) bv[j] = bias[tx * 8 + j];
#pragma unroll
    for (int i = 0; i < 4; ++i) {
        int n = n0 + ty * 4 + i;
        if (n >= N_NODES) continue;
        float o0[4], o1[4];
#pragma unroll
        for (int j = 0; j < 4; ++j) {
            float v0 = acc[i][j] + bv[j];
            float v1 = acc[i][j + 4] + bv[j + 4];
            if (RELU) { v0 = fmaxf(v0, 0.0f); v1 = fmaxf(v1, 0.0f); }
            o0[j] = v0; o1[j] = v1;
        }
        float* op = &out[(long)n * DIM + tx * 8];
        *reinterpret_cast<float4*>(op)     = make_float4(o0[0], o0[1], o0[2], o0[3]);
        *reinterpret_cast<float4*>(op + 4) = make_float4(o1[0], o1[1], o1[2], o1[3]);
    }
}

extern "C" void kernel_launch(void* const* d_in, const int* in_sizes, int n_in,
                              void* d_out, int out_size, void* d_ws, size_t ws_size,
                              hipStream_t stream) {
    const float* x   = (const float*)d_in[0];
    const int*   ei  = (const int*)d_in[1];
    const float* W1l = (const float*)d_in[2];
    const float* W1r = (const float*)d_in[3];
    const float* b1  = (const float*)d_in[4];
    const float* W2l = (const float*)d_in[5];
    const float* W2r = (const float*)d_in[6];
    const float* b2  = (const float*)d_in[7];
    const int* src = ei;        // edge_index[0]
    const int* dst = ei + NE;   // edge_index[1]

    float* ws  = (float*)d_ws;
    float* cnt = ws + CNT_OFF;
    float* agg = ws + AGG_OFF;
    float* h   = ws + H_OFF;
    float* out = (float*)d_out;

    // zero cnt + agg
    hipMemsetAsync(d_ws, 0, (size_t)(AGG_OFF + (size_t)N_NODES * DIM) * sizeof(float), stream);

    k_count<<<(NE + 255) / 256, 256, 0, stream>>>(dst, cnt);

    const int scatter_blocks = NE / 8;  // E*32 threads / 256
    k_scatter<<<scatter_blocks, 256, 0, stream>>>(src, dst, x, agg);

    const int layer_blocks = (N_NODES + 63) / 64;
    k_layer<true><<<layer_blocks, 256, 0, stream>>>(agg, cnt, x, W1l, W1r, b1, h);

    // re-zero agg for layer 2
    hipMemsetAsync(agg, 0, (size_t)N_NODES * DIM * sizeof(float), stream);

    k_scatter<<<scatter_blocks, 256, 0, stream>>>(src, dst, h, agg);

    k_layer<false><<<layer_blocks, 256, 0, stream>>>(agg, cnt, h, W2l, W2r, b2, out);
}

// Round 2
// 803.943 us; speedup vs baseline: 7.1472x; 7.1472x over previous
//
#include <hip/hip_runtime.h>

#define N_NODES 100000
#define NE      1600000
#define DIM     128

// ws layout (4-byte elements)
#define ROW_OFF   0                       // row_ptr / degree: N ints
#define PART_OFF  100352                  // scan partials: 128 ints
#define SRC_OFF   102400                  // sorted_src: NE ints
#define MEAN_OFF  (SRC_OFF + NE)          // mean: N*DIM floats
// total = 1,702,400 + 12,800,000 = 14,502,400 elems ≈ 58 MB

#define SCAN_B 1024
#define SCAN_NB ((N_NODES + SCAN_B - 1) / SCAN_B)   // 98

// ---------------- degree histogram (int atomics) ----------------
__global__ void k_hist(const int* __restrict__ dst, int* __restrict__ deg) {
    int e = blockIdx.x * 256 + threadIdx.x;
    if (e < NE) atomicAdd(&deg[dst[e]], 1);
}

// ---------------- exclusive scan, 3 kernels ----------------
__global__ __launch_bounds__(SCAN_B) void k_scan1(int* __restrict__ deg, int* __restrict__ part) {
    __shared__ int sm[SCAN_B];
    int tid = threadIdx.x;
    int i = blockIdx.x * SCAN_B + tid;
    int v = (i < N_NODES) ? deg[i] : 0;
    sm[tid] = v;
    __syncthreads();
    for (int off = 1; off < SCAN_B; off <<= 1) {
        int t = (tid >= off) ? sm[tid - off] : 0;
        __syncthreads();
        sm[tid] += t;
        __syncthreads();
    }
    if (i < N_NODES) deg[i] = sm[tid] - v;           // exclusive
    if (tid == SCAN_B - 1) part[blockIdx.x] = sm[tid]; // block sum
}

__global__ __launch_bounds__(128) void k_scan2(int* __restrict__ part) {
    __shared__ int sm[128];
    int tid = threadIdx.x;
    int v = (tid < SCAN_NB) ? part[tid] : 0;
    sm[tid] = v;
    __syncthreads();
    for (int off = 1; off < 128; off <<= 1) {
        int t = (tid >= off) ? sm[tid - off] : 0;
        __syncthreads();
        sm[tid] += t;
        __syncthreads();
    }
    if (tid < SCAN_NB) part[tid] = sm[tid] - v;      // exclusive
}

__global__ __launch_bounds__(SCAN_B) void k_scan3(int* __restrict__ deg, const int* __restrict__ part) {
    int i = blockIdx.x * SCAN_B + threadIdx.x;
    if (i < N_NODES) deg[i] += part[blockIdx.x];
}

// ---------------- edge placement (counting sort) ----------------
// After this kernel row_ptr[d] == end of row d (start = row_ptr[d-1], or 0).
__global__ void k_place(const int* __restrict__ src, const int* __restrict__ dst,
                        int* __restrict__ row_ptr, int* __restrict__ sorted_src) {
    int e = blockIdx.x * 256 + threadIdx.x;
    if (e >= NE) return;
    int d = dst[e];
    int slot = atomicAdd(&row_ptr[d], 1);
    sorted_src[slot] = src[e];
}

// ---------------- per-node mean aggregation (no atomics) ----------------
// one wave (64 lanes) per node, float2 per lane -> 512B coalesced per edge
__global__ __launch_bounds__(256) void k_agg(const int* __restrict__ row_end,
                                             const int* __restrict__ ssrc,
                                             const float* __restrict__ feat,
                                             float* __restrict__ mean) {
    int wave = (blockIdx.x * 256 + threadIdx.x) >> 6;
    if (wave >= N_NODES) return;
    int lane = threadIdx.x & 63;
    int start = (wave == 0) ? 0 : row_end[wave - 1];
    int end = row_end[wave];
    float ax = 0.0f, ay = 0.0f;
    for (int e = start; e < end; ++e) {
        int s = ssrc[e];
        float2 v = *reinterpret_cast<const float2*>(&feat[(long)s * DIM + lane * 2]);
        ax += v.x; ay += v.y;
    }
    float inv = (end > start) ? 1.0f / (float)(end - start) : 0.0f;
    *reinterpret_cast<float2*>(&mean[(long)wave * DIM + lane * 2]) =
        make_float2(ax * inv, ay * inv);
}

// ---------------- fused SAGE linear layer ----------------
// out[n][o] = mean[n] . Wl[o][:] + xin[n] . Wr[o][:] + bias[o]  (opt relu)
template <bool RELU>
__global__ __launch_bounds__(256) void k_layer(
    const float* __restrict__ mean, const float* __restrict__ xin,
    const float* __restrict__ Wl, const float* __restrict__ Wr,
    const float* __restrict__ bias, float* __restrict__ out)
{
    __shared__ float As[32][72];    // As[kk][row]
    __shared__ float Bs[32][132];   // Bs[kk][o]

    const int tid = threadIdx.x;
    const int ty = tid >> 4, tx = tid & 15;
    const int n0 = blockIdx.x * 64;

    float acc[4][8];
#pragma unroll
    for (int i = 0; i < 4; ++i)
#pragma unroll
        for (int j = 0; j < 8; ++j) acc[i][j] = 0.0f;

    const int ar = tid >> 2;            // 0..63 : A row
    const int akk0 = (tid & 3) * 8;     // 0,8,16,24
    const int bo = tid >> 1;            // 0..127 : B output row
    const int bkk0 = (tid & 1) * 16;    // 0,16

    for (int kb = 0; kb < 8; ++kb) {
        // ---- stage A (64 rows x 32 k), transposed ----
        {
            int n = n0 + ar;
            const float* Ap = (kb < 4) ? mean : xin;
            int kg = (kb & 3) * 32 + akk0;
            float vals[8];
            if (n < N_NODES) {
                float4 v0 = *reinterpret_cast<const float4*>(&Ap[(long)n * DIM + kg]);
                float4 v1 = *reinterpret_cast<const float4*>(&Ap[(long)n * DIM + kg + 4]);
                vals[0] = v0.x; vals[1] = v0.y; vals[2] = v0.z; vals[3] = v0.w;
                vals[4] = v1.x; vals[5] = v1.y; vals[6] = v1.z; vals[7] = v1.w;
            } else {
#pragma unroll
                for (int j = 0; j < 8; ++j) vals[j] = 0.0f;
            }
#pragma unroll
            for (int j = 0; j < 8; ++j) As[akk0 + j][ar] = vals[j];
        }
        // ---- stage B (32 k x 128 o) ----
        {
            const float* Wp = (kb < 4) ? Wl : Wr;
            int kg = (kb & 3) * 32 + bkk0;
            const float* wrow = &Wp[(long)bo * DIM + kg];
#pragma unroll
            for (int j = 0; j < 16; j += 4) {
                float4 w = *reinterpret_cast<const float4*>(&wrow[j]);
                Bs[bkk0 + j + 0][bo] = w.x;
                Bs[bkk0 + j + 1][bo] = w.y;
                Bs[bkk0 + j + 2][bo] = w.z;
                Bs[bkk0 + j + 3][bo] = w.w;
            }
        }
        __syncthreads();

#pragma unroll
        for (int kk = 0; kk < 32; ++kk) {
            float4 a = *reinterpret_cast<const float4*>(&As[kk][ty * 4]);
            float4 b0 = *reinterpret_cast<const float4*>(&Bs[kk][tx * 8]);
            float4 b1 = *reinterpret_cast<const float4*>(&Bs[kk][tx * 8 + 4]);
            float av[4] = {a.x, a.y, a.z, a.w};
            float bv[8] = {b0.x, b0.y, b0.z, b0.w, b1.x, b1.y, b1.z, b1.w};
#pragma unroll
            for (int i = 0; i < 4; ++i)
#pragma unroll
                for (int j = 0; j < 8; ++j)
                    acc[i][j] = fmaf(av[i], bv[j], acc[i][j]);
        }
        __syncthreads();
    }

    float bv[8];
#pragma unroll
    for (int j = 0; j < 8; ++j) bv[j] = bias[tx * 8 + j];
#pragma unroll
    for (int i = 0; i < 4; ++i) {
        int n = n0 + ty * 4 + i;
        if (n >= N_NODES) continue;
        float o0[4], o1[4];
#pragma unroll
        for (int j = 0; j < 4; ++j) {
            float v0 = acc[i][j] + bv[j];
            float v1 = acc[i][j + 4] + bv[j + 4];
            if (RELU) { v0 = fmaxf(v0, 0.0f); v1 = fmaxf(v1, 0.0f); }
            o0[j] = v0; o1[j] = v1;
        }
        float* op = &out[(long)n * DIM + tx * 8];
        *reinterpret_cast<float4*>(op)     = make_float4(o0[0], o0[1], o0[2], o0[3]);
        *reinterpret_cast<float4*>(op + 4) = make_float4(o1[0], o1[1], o1[2], o1[3]);
    }
}

extern "C" void kernel_launch(void* const* d_in, const int* in_sizes, int n_in,
                              void* d_out, int out_size, void* d_ws, size_t ws_size,
                              hipStream_t stream) {
    const float* x   = (const float*)d_in[0];
    const int*   ei  = (const int*)d_in[1];
    const float* W1l = (const float*)d_in[2];
    const float* W1r = (const float*)d_in[3];
    const float* b1  = (const float*)d_in[4];
    const float* W2l = (const float*)d_in[5];
    const float* W2r = (const float*)d_in[6];
    const float* b2  = (const float*)d_in[7];
    const int* src = ei;        // edge_index[0]
    const int* dst = ei + NE;   // edge_index[1]

    int*   wsi      = (int*)d_ws;
    int*   row_ptr  = wsi + ROW_OFF;
    int*   part     = wsi + PART_OFF;
    int*   ssrc     = wsi + SRC_OFF;
    float* mean     = (float*)d_ws + MEAN_OFF;
    float* out      = (float*)d_out;
    float* h        = out;   // layer-1 output lives in d_out (no cross-block hazard)

    // zero degree array
    hipMemsetAsync(row_ptr, 0, N_NODES * sizeof(int), stream);

    const int eb = (NE + 255) / 256;
    k_hist<<<eb, 256, 0, stream>>>(dst, row_ptr);
    k_scan1<<<SCAN_NB, SCAN_B, 0, stream>>>(row_ptr, part);
    k_scan2<<<1, 128, 0, stream>>>(part);
    k_scan3<<<SCAN_NB, SCAN_B, 0, stream>>>(row_ptr, part);
    k_place<<<eb, 256, 0, stream>>>(src, dst, row_ptr, ssrc);

    const int agg_blocks = N_NODES / 4;        // 4 waves (nodes) per block
    const int layer_blocks = (N_NODES + 63) / 64;

    // layer 1
    k_agg<<<agg_blocks, 256, 0, stream>>>(row_ptr, ssrc, x, mean);
    k_layer<true><<<layer_blocks, 256, 0, stream>>>(mean, x, W1l, W1r, b1, h);

    // layer 2
    k_agg<<<agg_blocks, 256, 0, stream>>>(row_ptr, ssrc, h, mean);
    k_layer<false><<<layer_blocks, 256, 0, stream>>>(mean, h, W2l, W2r, b2, out);
}

// Round 4
// 677.305 us; speedup vs baseline: 8.4835x; 1.1870x over previous
//
#include <hip/hip_runtime.h>
#include <stdint.h>

#define N_NODES 100000
#define NE      1600000
#define DIM     128

typedef __attribute__((ext_vector_type(8)))  __bf16 bf16x8;
typedef __attribute__((ext_vector_type(16))) float  f32x16;

// ---- ws byte offsets ----
#define ROW_B  0u            // row_ptr: N ints
#define PART_B 401408u       // scan partials: 128 ints
#define SRC_B  409600u       // sorted_src: NE ints
#define XB_B   6809600u      // x  bf16: N*128
#define HB_B   32409600u     // h  bf16: N*128
#define MB_B   58009600u     // mean bf16: N*128
#define W1_B   83609600u     // wcat1 bf16: 128*256
#define W2_B   83675136u     // wcat2 bf16: 128*256
// end 83,740,672 B — round-1 proved ws_size >= ~103 MB

#define SCAN_B 1024
#define SCAN_NB 98

// ---------------- helpers ----------------
__device__ __forceinline__ uint32_t f2b_rne(float f) {
    uint32_t u = __float_as_uint(f);
    return (u + 0x7FFFu + ((u >> 16) & 1u)) >> 16;
}
__device__ __forceinline__ float b2f_lo(uint32_t u) { return __uint_as_float(u << 16); }
__device__ __forceinline__ float b2f_hi(uint32_t u) { return __uint_as_float(u & 0xFFFF0000u); }

// ---------------- degree histogram ----------------
__global__ void k_hist(const int* __restrict__ dst, int* __restrict__ deg) {
    int e = blockIdx.x * 256 + threadIdx.x;
    if (e < NE) atomicAdd(&deg[dst[e]], 1);
}

// ---------------- exclusive scan (3 kernels) ----------------
__global__ __launch_bounds__(SCAN_B) void k_scan1(int* __restrict__ deg, int* __restrict__ part) {
    __shared__ int sm[SCAN_B];
    int tid = threadIdx.x;
    int i = blockIdx.x * SCAN_B + tid;
    int v = (i < N_NODES) ? deg[i] : 0;
    sm[tid] = v;
    __syncthreads();
    for (int off = 1; off < SCAN_B; off <<= 1) {
        int t = (tid >= off) ? sm[tid - off] : 0;
        __syncthreads();
        sm[tid] += t;
        __syncthreads();
    }
    if (i < N_NODES) deg[i] = sm[tid] - v;
    if (tid == SCAN_B - 1) part[blockIdx.x] = sm[tid];
}

__global__ __launch_bounds__(128) void k_scan2(int* __restrict__ part) {
    __shared__ int sm[128];
    int tid = threadIdx.x;
    int v = (tid < SCAN_NB) ? part[tid] : 0;
    sm[tid] = v;
    __syncthreads();
    for (int off = 1; off < 128; off <<= 1) {
        int t = (tid >= off) ? sm[tid - off] : 0;
        __syncthreads();
        sm[tid] += t;
        __syncthreads();
    }
    if (tid < SCAN_NB) part[tid] = sm[tid] - v;
}

__global__ __launch_bounds__(SCAN_B) void k_scan3(int* __restrict__ deg, const int* __restrict__ part) {
    int i = blockIdx.x * SCAN_B + threadIdx.x;
    if (i < N_NODES) deg[i] += part[blockIdx.x];
}

// ---------------- edge placement (counting sort) ----------------
__global__ void k_place(const int* __restrict__ src, const int* __restrict__ dst,
                        int* __restrict__ row_ptr, int* __restrict__ sorted_src) {
    int e = blockIdx.x * 256 + threadIdx.x;
    if (e >= NE) return;
    int d = dst[e];
    int slot = atomicAdd(&row_ptr[d], 1);
    sorted_src[slot] = src[e];
}

// ---------------- f32 -> bf16 conversions ----------------
__global__ __launch_bounds__(256) void k_cvt_x(const float* __restrict__ x, uint32_t* __restrict__ xb) {
    size_t i = (size_t)blockIdx.x * 256 + threadIdx.x;       // 4 elems each
    if (i * 4 >= (size_t)N_NODES * DIM) return;
    float4 v = *reinterpret_cast<const float4*>(x + i * 4);
    uint2 o;
    o.x = f2b_rne(v.x) | (f2b_rne(v.y) << 16);
    o.y = f2b_rne(v.z) | (f2b_rne(v.w) << 16);
    *reinterpret_cast<uint2*>(xb + i * 2) = o;
}

// wcat[n][0:128]=W_l[n][:], wcat[n][128:256]=W_r[n][:]  (bf16)
__global__ __launch_bounds__(256) void k_cvt_w(
    const float* __restrict__ W1l, const float* __restrict__ W1r,
    const float* __restrict__ W2l, const float* __restrict__ W2r,
    uint16_t* __restrict__ w1, uint16_t* __restrict__ w2) {
    int gid = blockIdx.x * 256 + threadIdx.x;                // 16384 total
    int layer = gid >> 13;
    int e = (gid & 8191) * 4;
    int row = e >> 8;
    int col = e & 255;
    const float* Wl = layer ? W2l : W1l;
    const float* Wr = layer ? W2r : W1r;
    const float* srcm = (col < 128) ? Wl : Wr;
    int c = col & 127;
    float4 v = *reinterpret_cast<const float4*>(&srcm[row * 128 + c]);
    uint2 o;
    o.x = f2b_rne(v.x) | (f2b_rne(v.y) << 16);
    o.y = f2b_rne(v.z) | (f2b_rne(v.w) << 16);
    uint16_t* wd = layer ? w2 : w1;
    *reinterpret_cast<uint2*>(&wd[row * 256 + col]) = o;
}

// ---------------- per-node mean aggregation (round-2 proven loop, bf16) ----
__global__ __launch_bounds__(256) void k_agg(const int* __restrict__ row_end,
                                             const int* __restrict__ ssrc,
                                             const uint32_t* __restrict__ featb,
                                             uint32_t* __restrict__ meanb) {
    int node = (int)((blockIdx.x * 256 + threadIdx.x) >> 6);
    if (node >= N_NODES) return;
    int lane = threadIdx.x & 63;
    int start = node ? row_end[node - 1] : 0;
    int end = row_end[node];
    float ax = 0.0f, ay = 0.0f;
    for (int e = start; e < end; ++e) {
        int s = ssrc[e];
        uint32_t u = featb[(size_t)s * 64 + lane];
        ax += b2f_lo(u); ay += b2f_hi(u);
    }
    float inv = (end > start) ? 1.0f / (float)(end - start) : 0.0f;
    meanb[(size_t)node * 64 + lane] = f2b_rne(ax * inv) | (f2b_rne(ay * inv) << 16);
}

// ---------------- MFMA SAGE layer (no LDS; B fragments from global/L1) ----
// out[n][o] = sum_k A[n][k] * wcat[o][k] + bias[o], A=[mean|x], K=256.
// block: 256 thr = 4 waves; tile 128 rows x 128 cols; wave (wm,wn) does 64x64
// via 2x2 mfma_f32_32x32x16_bf16 tiles.
template <bool RELU, bool BF16_OUT>
__global__ __launch_bounds__(256) void k_layer(
    const uint16_t* __restrict__ meanb, const uint16_t* __restrict__ xb,
    const uint16_t* __restrict__ wcat, const float* __restrict__ bias,
    void* __restrict__ outp)
{
    const int tid = threadIdx.x;
    const int lane = tid & 63;
    const int w = tid >> 6;
    const int wm = (w >> 1) * 64, wn = (w & 1) * 64;
    const int lrow = lane & 31, lk = (lane >> 5) * 8;
    const int base = blockIdx.x * 128;

    f32x16 acc00, acc01, acc10, acc11;
#pragma unroll
    for (int r = 0; r < 16; ++r) { acc00[r] = 0.f; acc01[r] = 0.f; acc10[r] = 0.f; acc11[r] = 0.f; }

    int r0 = base + wm + lrow;
    int r1 = r0 + 32;
    if (r0 > N_NODES - 1) r0 = N_NODES - 1;
    if (r1 > N_NODES - 1) r1 = N_NODES - 1;
    const uint16_t* a0m = meanb + (size_t)r0 * DIM + lk;
    const uint16_t* a1m = meanb + (size_t)r1 * DIM + lk;
    const uint16_t* a0x = xb   + (size_t)r0 * DIM + lk;
    const uint16_t* a1x = xb   + (size_t)r1 * DIM + lk;
    const uint16_t* b0p = wcat + (size_t)(wn + lrow) * 256 + lk;
    const uint16_t* b1p = wcat + (size_t)(wn + 32 + lrow) * 256 + lk;

#pragma unroll
    for (int ks = 0; ks < 16; ++ks) {
        const int klocal = (ks & 7) * 16;
        bf16x8 a0 = *reinterpret_cast<const bf16x8*>(((ks < 8) ? a0m : a0x) + klocal);
        bf16x8 a1 = *reinterpret_cast<const bf16x8*>(((ks < 8) ? a1m : a1x) + klocal);
        bf16x8 b0 = *reinterpret_cast<const bf16x8*>(b0p + ks * 16);
        bf16x8 b1 = *reinterpret_cast<const bf16x8*>(b1p + ks * 16);
        acc00 = __builtin_amdgcn_mfma_f32_32x32x16_bf16(a0, b0, acc00, 0, 0, 0);
        acc01 = __builtin_amdgcn_mfma_f32_32x32x16_bf16(a0, b1, acc01, 0, 0, 0);
        acc10 = __builtin_amdgcn_mfma_f32_32x32x16_bf16(a1, b0, acc10, 0, 0, 0);
        acc11 = __builtin_amdgcn_mfma_f32_32x32x16_bf16(a1, b1, acc11, 0, 0, 0);
    }

    const float bc0 = bias[wn + lrow];
    const float bc1 = bias[wn + 32 + lrow];
    const int hi4 = 4 * (lane >> 5);

#define STORE_TILE(ACC, MI, NI, BB)                                            \
    {                                                                          \
        const int colg = wn + (NI) * 32 + lrow;                                \
        _Pragma("unroll")                                                      \
        for (int r = 0; r < 16; ++r) {                                         \
            int rowg = base + wm + (MI) * 32 + (r & 3) + 8 * (r >> 2) + hi4;   \
            if (rowg < N_NODES) {                                              \
                float v = ACC[r] + (BB);                                       \
                if (RELU) v = fmaxf(v, 0.0f);                                  \
                if (BF16_OUT)                                                  \
                    ((uint16_t*)outp)[(size_t)rowg * DIM + colg] =             \
                        (uint16_t)f2b_rne(v);                                  \
                else                                                           \
                    ((float*)outp)[(size_t)rowg * DIM + colg] = v;             \
            }                                                                  \
        }                                                                      \
    }
    STORE_TILE(acc00, 0, 0, bc0)
    STORE_TILE(acc01, 0, 1, bc1)
    STORE_TILE(acc10, 1, 0, bc0)
    STORE_TILE(acc11, 1, 1, bc1)
#undef STORE_TILE
}

extern "C" void kernel_launch(void* const* d_in, const int* in_sizes, int n_in,
                              void* d_out, int out_size, void* d_ws, size_t ws_size,
                              hipStream_t stream) {
    const float* x   = (const float*)d_in[0];
    const int*   ei  = (const int*)d_in[1];
    const float* W1l = (const float*)d_in[2];
    const float* W1r = (const float*)d_in[3];
    const float* b1  = (const float*)d_in[4];
    const float* W2l = (const float*)d_in[5];
    const float* W2r = (const float*)d_in[6];
    const float* b2  = (const float*)d_in[7];
    const int* src = ei;
    const int* dst = ei + NE;

    char* wsb = (char*)d_ws;
    int*      row_ptr = (int*)(wsb + ROW_B);
    int*      part    = (int*)(wsb + PART_B);
    int*      ssrc    = (int*)(wsb + SRC_B);
    uint32_t* xb32    = (uint32_t*)(wsb + XB_B);
    uint16_t* xb16    = (uint16_t*)(wsb + XB_B);
    uint32_t* hb32    = (uint32_t*)(wsb + HB_B);
    uint16_t* hb16    = (uint16_t*)(wsb + HB_B);
    uint32_t* mb32    = (uint32_t*)(wsb + MB_B);
    uint16_t* mb16    = (uint16_t*)(wsb + MB_B);
    uint16_t* w1      = (uint16_t*)(wsb + W1_B);
    uint16_t* w2      = (uint16_t*)(wsb + W2_B);
    float*    outf    = (float*)d_out;

    hipMemsetAsync(row_ptr, 0, N_NODES * sizeof(int), stream);

    const int eb = (NE + 255) / 256;
    k_hist <<<eb, 256, 0, stream>>>(dst, row_ptr);
    k_scan1<<<SCAN_NB, SCAN_B, 0, stream>>>(row_ptr, part);
    k_scan2<<<1, 128, 0, stream>>>(part);
    k_scan3<<<SCAN_NB, SCAN_B, 0, stream>>>(row_ptr, part);
    k_place<<<eb, 256, 0, stream>>>(src, dst, row_ptr, ssrc);

    k_cvt_x<<<12500, 256, 0, stream>>>(x, xb32);
    k_cvt_w<<<64, 256, 0, stream>>>(W1l, W1r, W2l, W2r, w1, w2);

    const int agg_blocks = N_NODES / 4;            // one wave per node
    const int layer_blocks = (N_NODES + 127) / 128;

    // layer 1
    k_agg<<<agg_blocks, 256, 0, stream>>>(row_ptr, ssrc, xb32, mb32);
    k_layer<true, true><<<layer_blocks, 256, 0, stream>>>(mb16, xb16, w1, b1, (void*)hb16);

    // layer 2
    k_agg<<<agg_blocks, 256, 0, stream>>>(row_ptr, ssrc, hb32, mb32);
    k_layer<false, false><<<layer_blocks, 256, 0, stream>>>(mb16, hb16, w2, b2, (void*)outf);
}

// Round 5
// 505.215 us; speedup vs baseline: 11.3732x; 1.3406x over previous
//
#include <hip/hip_runtime.h>
#include <stdint.h>

#define N_NODES 100000
#define NE      1600000
#define DIM     128

typedef __attribute__((ext_vector_type(8)))  __bf16 bf16x8;
typedef __attribute__((ext_vector_type(16))) float  f32x16;

// ---- ws byte offsets ----
#define ROW_B  0u            // row_ptr: N ints
#define PART_B 401408u       // scan partials: 128 ints
#define SRC_B  409600u       // sorted_src: NE ints
#define XB_B   6809600u      // x  bf16: N*128
#define HB_B   32409600u     // h  bf16: N*128
#define MB_B   58009600u     // mean bf16: N*128
#define W1_B   83609600u     // wcat1 bf16: 128*256
#define W2_B   83675136u     // wcat2 bf16: 128*256

#define SCAN_B 1024
#define SCAN_NB 98

// ---------------- helpers ----------------
__device__ __forceinline__ uint32_t f2b_rne(float f) {
    uint32_t u = __float_as_uint(f);
    return (u + 0x7FFFu + ((u >> 16) & 1u)) >> 16;
}
__device__ __forceinline__ float b2f_lo(uint32_t u) { return __uint_as_float(u << 16); }
__device__ __forceinline__ float b2f_hi(uint32_t u) { return __uint_as_float(u & 0xFFFF0000u); }

// ---------------- degree histogram ----------------
__global__ void k_hist(const int* __restrict__ dst, int* __restrict__ deg) {
    int e = blockIdx.x * 256 + threadIdx.x;
    if (e < NE) atomicAdd(&deg[dst[e]], 1);
}

// ---------------- exclusive scan (3 kernels) ----------------
__global__ __launch_bounds__(SCAN_B) void k_scan1(int* __restrict__ deg, int* __restrict__ part) {
    __shared__ int sm[SCAN_B];
    int tid = threadIdx.x;
    int i = blockIdx.x * SCAN_B + tid;
    int v = (i < N_NODES) ? deg[i] : 0;
    sm[tid] = v;
    __syncthreads();
    for (int off = 1; off < SCAN_B; off <<= 1) {
        int t = (tid >= off) ? sm[tid - off] : 0;
        __syncthreads();
        sm[tid] += t;
        __syncthreads();
    }
    if (i < N_NODES) deg[i] = sm[tid] - v;
    if (tid == SCAN_B - 1) part[blockIdx.x] = sm[tid];
}

__global__ __launch_bounds__(128) void k_scan2(int* __restrict__ part) {
    __shared__ int sm[128];
    int tid = threadIdx.x;
    int v = (tid < SCAN_NB) ? part[tid] : 0;
    sm[tid] = v;
    __syncthreads();
    for (int off = 1; off < 128; off <<= 1) {
        int t = (tid >= off) ? sm[tid - off] : 0;
        __syncthreads();
        sm[tid] += t;
        __syncthreads();
    }
    if (tid < SCAN_NB) part[tid] = sm[tid] - v;
}

__global__ __launch_bounds__(SCAN_B) void k_scan3(int* __restrict__ deg, const int* __restrict__ part) {
    int i = blockIdx.x * SCAN_B + threadIdx.x;
    if (i < N_NODES) deg[i] += part[blockIdx.x];
}

// ---------------- edge placement (counting sort) ----------------
__global__ void k_place(const int* __restrict__ src, const int* __restrict__ dst,
                        int* __restrict__ row_ptr, int* __restrict__ sorted_src) {
    int e = blockIdx.x * 256 + threadIdx.x;
    if (e >= NE) return;
    int d = dst[e];
    int slot = atomicAdd(&row_ptr[d], 1);
    sorted_src[slot] = src[e];
}

// ---------------- f32 -> bf16 conversions ----------------
__global__ __launch_bounds__(256) void k_cvt_x(const float* __restrict__ x, uint32_t* __restrict__ xb) {
    size_t i = (size_t)blockIdx.x * 256 + threadIdx.x;       // 4 elems each
    if (i * 4 >= (size_t)N_NODES * DIM) return;
    float4 v = *reinterpret_cast<const float4*>(x + i * 4);
    uint2 o;
    o.x = f2b_rne(v.x) | (f2b_rne(v.y) << 16);
    o.y = f2b_rne(v.z) | (f2b_rne(v.w) << 16);
    *reinterpret_cast<uint2*>(xb + i * 2) = o;
}

// wcat[n][0:128]=W_l[n][:], wcat[n][128:256]=W_r[n][:]  (bf16)
__global__ __launch_bounds__(256) void k_cvt_w(
    const float* __restrict__ W1l, const float* __restrict__ W1r,
    const float* __restrict__ W2l, const float* __restrict__ W2r,
    uint16_t* __restrict__ w1, uint16_t* __restrict__ w2) {
    int gid = blockIdx.x * 256 + threadIdx.x;                // 16384 total
    int layer = gid >> 13;
    int e = (gid & 8191) * 4;
    int row = e >> 8;
    int col = e & 255;
    const float* Wl = layer ? W2l : W1l;
    const float* Wr = layer ? W2r : W1r;
    const float* srcm = (col < 128) ? Wl : Wr;
    int c = col & 127;
    float4 v = *reinterpret_cast<const float4*>(&srcm[row * 128 + c]);
    uint2 o;
    o.x = f2b_rne(v.x) | (f2b_rne(v.y) << 16);
    o.y = f2b_rne(v.z) | (f2b_rne(v.w) << 16);
    uint16_t* wd = layer ? w2 : w1;
    *reinterpret_cast<uint2*>(&wd[row * 256 + col]) = o;
}

// ---------------- per-node mean aggregation (unroll-8 ILP, bf16) ----------
// one wave per node; lane holds 2 feats. 8 independent row-gathers in
// flight per chunk to break the per-edge dependent-load latency chain.
__global__ __launch_bounds__(256) void k_agg(const int* __restrict__ row_end,
                                             const int* __restrict__ ssrc,
                                             const uint32_t* __restrict__ featb,
                                             uint32_t* __restrict__ meanb) {
    int node = (int)((blockIdx.x * 256 + threadIdx.x) >> 6);
    if (node >= N_NODES) return;
    int lane = threadIdx.x & 63;
    int start = node ? row_end[node - 1] : 0;
    int end = row_end[node];

    float ax0 = 0.f, ay0 = 0.f, ax1 = 0.f, ay1 = 0.f;
    float ax2 = 0.f, ay2 = 0.f, ax3 = 0.f, ay3 = 0.f;

    int e = start;
    for (; e + 8 <= end; e += 8) {
        int s0 = ssrc[e + 0], s1 = ssrc[e + 1], s2 = ssrc[e + 2], s3 = ssrc[e + 3];
        int s4 = ssrc[e + 4], s5 = ssrc[e + 5], s6 = ssrc[e + 6], s7 = ssrc[e + 7];
        uint32_t u0 = featb[(size_t)s0 * 64 + lane];
        uint32_t u1 = featb[(size_t)s1 * 64 + lane];
        uint32_t u2 = featb[(size_t)s2 * 64 + lane];
        uint32_t u3 = featb[(size_t)s3 * 64 + lane];
        uint32_t u4 = featb[(size_t)s4 * 64 + lane];
        uint32_t u5 = featb[(size_t)s5 * 64 + lane];
        uint32_t u6 = featb[(size_t)s6 * 64 + lane];
        uint32_t u7 = featb[(size_t)s7 * 64 + lane];
        ax0 += b2f_lo(u0); ay0 += b2f_hi(u0);
        ax1 += b2f_lo(u1); ay1 += b2f_hi(u1);
        ax2 += b2f_lo(u2); ay2 += b2f_hi(u2);
        ax3 += b2f_lo(u3); ay3 += b2f_hi(u3);
        ax0 += b2f_lo(u4); ay0 += b2f_hi(u4);
        ax1 += b2f_lo(u5); ay1 += b2f_hi(u5);
        ax2 += b2f_lo(u6); ay2 += b2f_hi(u6);
        ax3 += b2f_lo(u7); ay3 += b2f_hi(u7);
    }
    if (e + 4 <= end) {
        int s0 = ssrc[e + 0], s1 = ssrc[e + 1], s2 = ssrc[e + 2], s3 = ssrc[e + 3];
        uint32_t u0 = featb[(size_t)s0 * 64 + lane];
        uint32_t u1 = featb[(size_t)s1 * 64 + lane];
        uint32_t u2 = featb[(size_t)s2 * 64 + lane];
        uint32_t u3 = featb[(size_t)s3 * 64 + lane];
        ax0 += b2f_lo(u0); ay0 += b2f_hi(u0);
        ax1 += b2f_lo(u1); ay1 += b2f_hi(u1);
        ax2 += b2f_lo(u2); ay2 += b2f_hi(u2);
        ax3 += b2f_lo(u3); ay3 += b2f_hi(u3);
        e += 4;
    }
    for (; e < end; ++e) {
        int s = ssrc[e];
        uint32_t u = featb[(size_t)s * 64 + lane];
        ax0 += b2f_lo(u); ay0 += b2f_hi(u);
    }

    int cnt = end - start;
    float inv = cnt > 0 ? 1.0f / (float)cnt : 0.0f;
    float ax = ((ax0 + ax1) + (ax2 + ax3)) * inv;
    float ay = ((ay0 + ay1) + (ay2 + ay3)) * inv;
    meanb[(size_t)node * 64 + lane] = f2b_rne(ax) | (f2b_rne(ay) << 16);
}

// ---------------- MFMA SAGE layer (no LDS; B fragments from global/L1) ----
template <bool RELU, bool BF16_OUT>
__global__ __launch_bounds__(256) void k_layer(
    const uint16_t* __restrict__ meanb, const uint16_t* __restrict__ xb,
    const uint16_t* __restrict__ wcat, const float* __restrict__ bias,
    void* __restrict__ outp)
{
    const int tid = threadIdx.x;
    const int lane = tid & 63;
    const int w = tid >> 6;
    const int wm = (w >> 1) * 64, wn = (w & 1) * 64;
    const int lrow = lane & 31, lk = (lane >> 5) * 8;
    const int base = blockIdx.x * 128;

    f32x16 acc00, acc01, acc10, acc11;
#pragma unroll
    for (int r = 0; r < 16; ++r) { acc00[r] = 0.f; acc01[r] = 0.f; acc10[r] = 0.f; acc11[r] = 0.f; }

    int r0 = base + wm + lrow;
    int r1 = r0 + 32;
    if (r0 > N_NODES - 1) r0 = N_NODES - 1;
    if (r1 > N_NODES - 1) r1 = N_NODES - 1;
    const uint16_t* a0m = meanb + (size_t)r0 * DIM + lk;
    const uint16_t* a1m = meanb + (size_t)r1 * DIM + lk;
    const uint16_t* a0x = xb   + (size_t)r0 * DIM + lk;
    const uint16_t* a1x = xb   + (size_t)r1 * DIM + lk;
    const uint16_t* b0p = wcat + (size_t)(wn + lrow) * 256 + lk;
    const uint16_t* b1p = wcat + (size_t)(wn + 32 + lrow) * 256 + lk;

#pragma unroll
    for (int ks = 0; ks < 16; ++ks) {
        const int klocal = (ks & 7) * 16;
        bf16x8 a0 = *reinterpret_cast<const bf16x8*>(((ks < 8) ? a0m : a0x) + klocal);
        bf16x8 a1 = *reinterpret_cast<const bf16x8*>(((ks < 8) ? a1m : a1x) + klocal);
        bf16x8 b0 = *reinterpret_cast<const bf16x8*>(b0p + ks * 16);
        bf16x8 b1 = *reinterpret_cast<const bf16x8*>(b1p + ks * 16);
        acc00 = __builtin_amdgcn_mfma_f32_32x32x16_bf16(a0, b0, acc00, 0, 0, 0);
        acc01 = __builtin_amdgcn_mfma_f32_32x32x16_bf16(a0, b1, acc01, 0, 0, 0);
        acc10 = __builtin_amdgcn_mfma_f32_32x32x16_bf16(a1, b0, acc10, 0, 0, 0);
        acc11 = __builtin_amdgcn_mfma_f32_32x32x16_bf16(a1, b1, acc11, 0, 0, 0);
    }

    const float bc0 = bias[wn + lrow];
    const float bc1 = bias[wn + 32 + lrow];
    const int hi4 = 4 * (lane >> 5);

#define STORE_TILE(ACC, MI, NI, BB)                                            \
    {                                                                          \
        const int colg = wn + (NI) * 32 + lrow;                                \
        _Pragma("unroll")                                                      \
        for (int r = 0; r < 16; ++r) {                                         \
            int rowg = base + wm + (MI) * 32 + (r & 3) + 8 * (r >> 2) + hi4;   \
            if (rowg < N_NODES) {                                              \
                float v = ACC[r] + (BB);                                       \
                if (RELU) v = fmaxf(v, 0.0f);                                  \
                if (BF16_OUT)                                                  \
                    ((uint16_t*)outp)[(size_t)rowg * DIM + colg] =             \
                        (uint16_t)f2b_rne(v);                                  \
                else                                                           \
                    ((float*)outp)[(size_t)rowg * DIM + colg] = v;             \
            }                                                                  \
        }                                                                      \
    }
    STORE_TILE(acc00, 0, 0, bc0)
    STORE_TILE(acc01, 0, 1, bc1)
    STORE_TILE(acc10, 1, 0, bc0)
    STORE_TILE(acc11, 1, 1, bc1)
#undef STORE_TILE
}

extern "C" void kernel_launch(void* const* d_in, const int* in_sizes, int n_in,
                              void* d_out, int out_size, void* d_ws, size_t ws_size,
                              hipStream_t stream) {
    const float* x   = (const float*)d_in[0];
    const int*   ei  = (const int*)d_in[1];
    const float* W1l = (const float*)d_in[2];
    const float* W1r = (const float*)d_in[3];
    const float* b1  = (const float*)d_in[4];
    const float* W2l = (const float*)d_in[5];
    const float* W2r = (const float*)d_in[6];
    const float* b2  = (const float*)d_in[7];
    const int* src = ei;
    const int* dst = ei + NE;

    char* wsb = (char*)d_ws;
    int*      row_ptr = (int*)(wsb + ROW_B);
    int*      part    = (int*)(wsb + PART_B);
    int*      ssrc    = (int*)(wsb + SRC_B);
    uint32_t* xb32    = (uint32_t*)(wsb + XB_B);
    uint16_t* xb16    = (uint16_t*)(wsb + XB_B);
    uint32_t* hb32    = (uint32_t*)(wsb + HB_B);
    uint16_t* hb16    = (uint16_t*)(wsb + HB_B);
    uint32_t* mb32    = (uint32_t*)(wsb + MB_B);
    uint16_t* mb16    = (uint16_t*)(wsb + MB_B);
    uint16_t* w1      = (uint16_t*)(wsb + W1_B);
    uint16_t* w2      = (uint16_t*)(wsb + W2_B);
    float*    outf    = (float*)d_out;

    hipMemsetAsync(row_ptr, 0, N_NODES * sizeof(int), stream);

    const int eb = (NE + 255) / 256;
    k_hist <<<eb, 256, 0, stream>>>(dst, row_ptr);
    k_scan1<<<SCAN_NB, SCAN_B, 0, stream>>>(row_ptr, part);
    k_scan2<<<1, 128, 0, stream>>>(part);
    k_scan3<<<SCAN_NB, SCAN_B, 0, stream>>>(row_ptr, part);
    k_place<<<eb, 256, 0, stream>>>(src, dst, row_ptr, ssrc);

    k_cvt_x<<<12500, 256, 0, stream>>>(x, xb32);
    k_cvt_w<<<64, 256, 0, stream>>>(W1l, W1r, W2l, W2r, w1, w2);

    const int agg_blocks = N_NODES / 4;            // one wave per node
    const int layer_blocks = (N_NODES + 127) / 128;

    // layer 1
    k_agg<<<agg_blocks, 256, 0, stream>>>(row_ptr, ssrc, xb32, mb32);
    k_layer<true, true><<<layer_blocks, 256, 0, stream>>>(mb16, xb16, w1, b1, (void*)hb16);

    // layer 2
    k_agg<<<agg_blocks, 256, 0, stream>>>(row_ptr, ssrc, hb32, mb32);
    k_layer<false, false><<<layer_blocks, 256, 0, stream>>>(mb16, hb16, w2, b2, (void*)outf);
}

// Round 7
// 435.112 us; speedup vs baseline: 13.2056x; 1.1611x over previous
//
#include <hip/hip_runtime.h>
#include <stdint.h>

#define N_NODES 100000
#define NE      1600000
#define DIM     128
#define NBUCKET 391                  // ceil(N/256)

typedef __attribute__((ext_vector_type(8)))  __bf16 bf16x8;
typedef __attribute__((ext_vector_type(16))) float  f32x16;

// ---- ws byte offsets ----
#define ROW_B   0u           // rowptr: (N+1) ints (exclusive scan; rowptr[N]=NE)
#define PART_B  401408u      // scan partials: 128 ints
#define BCUR_B  401920u      // bucket cursors: 512 ints
#define SRC_B   409600u      // sorted_src: NE ints
#define XB_B    6809600u     // x  bf16: N*128
#define HB_B    32409600u    // h  bf16: N*128
#define MB_B    58009600u    // mean bf16: N*128
#define W1_B    83609600u    // wcat1 bf16: 128*256
#define W2_B    83675136u    // wcat2 bf16: 128*256
#define BPAIR_B 83740672u    // (src,dst) records: NE int2 = 12.8MB -> end ~96.5MB

#define SCAN_B 1024
#define SCAN_NB 98

// ---------------- helpers ----------------
__device__ __forceinline__ uint32_t f2b_rne(float f) {
    uint32_t u = __float_as_uint(f);
    return (u + 0x7FFFu + ((u >> 16) & 1u)) >> 16;
}
__device__ __forceinline__ float b2f_lo(uint32_t u) { return __uint_as_float(u << 16); }
__device__ __forceinline__ float b2f_hi(uint32_t u) { return __uint_as_float(u & 0xFFFF0000u); }

// ---------------- degree histogram ----------------
__global__ void k_hist(const int* __restrict__ dst, int* __restrict__ deg) {
    int e = blockIdx.x * 256 + threadIdx.x;
    if (e < NE) atomicAdd(&deg[dst[e]], 1);
}

// ---------------- exclusive scan (3 kernels) ----------------
__global__ __launch_bounds__(SCAN_B) void k_scan1(int* __restrict__ deg, int* __restrict__ part) {
    __shared__ int sm[SCAN_B];
    int tid = threadIdx.x;
    int i = blockIdx.x * SCAN_B + tid;
    int v = (i < N_NODES) ? deg[i] : 0;
    sm[tid] = v;
    __syncthreads();
    for (int off = 1; off < SCAN_B; off <<= 1) {
        int t = (tid >= off) ? sm[tid - off] : 0;
        __syncthreads();
        sm[tid] += t;
        __syncthreads();
    }
    if (i < N_NODES) deg[i] = sm[tid] - v;
    if (tid == SCAN_B - 1) part[blockIdx.x] = sm[tid];
}

__global__ __launch_bounds__(128) void k_scan2(int* __restrict__ part, int* __restrict__ rowptr) {
    __shared__ int sm[128];
    int tid = threadIdx.x;
    int v = (tid < SCAN_NB) ? part[tid] : 0;
    sm[tid] = v;
    __syncthreads();
    for (int off = 1; off < 128; off <<= 1) {
        int t = (tid >= off) ? sm[tid - off] : 0;
        __syncthreads();
        sm[tid] += t;
        __syncthreads();
    }
    if (tid < SCAN_NB) part[tid] = sm[tid] - v;
    if (tid == 0) rowptr[N_NODES] = NE;     // sentinel
}

__global__ __launch_bounds__(SCAN_B) void k_scan3(int* __restrict__ deg, const int* __restrict__ part) {
    int i = blockIdx.x * SCAN_B + threadIdx.x;
    if (i < N_NODES) deg[i] += part[blockIdx.x];
}

// ---------------- bucket cursor init ----------------
__global__ void k_binit(const int* __restrict__ rowptr, int* __restrict__ bcur) {
    int b = blockIdx.x * 256 + threadIdx.x;
    if (b < NBUCKET) bcur[b] = rowptr[b << 8];
}

// ---------------- phase A: bucket edges by dst>>8 (dense 8B writes) ------
#define BK_WG   512
#define BK_EPW  3125          // NE / BK_WG
__global__ __launch_bounds__(1024) void k_bucket(
    const int* __restrict__ src, const int* __restrict__ dst,
    int* __restrict__ bcur, int2* __restrict__ bpair) {
    __shared__ int hist[392];
    __shared__ int base[392];
    __shared__ int cur[392];
    const int tid = threadIdx.x;
    const int e0 = blockIdx.x * BK_EPW;
    const int e1 = e0 + BK_EPW;

    if (tid < 392) { hist[tid] = 0; cur[tid] = 0; }
    __syncthreads();
    for (int e = e0 + tid; e < e1; e += 1024)
        atomicAdd(&hist[dst[e] >> 8], 1);
    __syncthreads();
    if (tid < 392) {
        int h = hist[tid];
        base[tid] = h ? atomicAdd(&bcur[tid], h) : 0;
    }
    __syncthreads();
    for (int e = e0 + tid; e < e1; e += 1024) {
        int d = dst[e];
        int b = d >> 8;
        int loc = atomicAdd(&cur[b], 1);
        bpair[(size_t)(base[b] + loc)] = make_int2(src[e], d);
    }
}

// ---------------- phase B: within-bucket counting place (dense writes) ----
__global__ __launch_bounds__(256) void k_sortb(
    const int* __restrict__ rowptr, const int2* __restrict__ bpair,
    int* __restrict__ ssrc) {
    __shared__ int cur[256];
    const int b = blockIdx.x;
    const int tid = threadIdx.x;
    const int n0 = b << 8;
    int idx = n0 + tid;
    cur[tid] = (idx < N_NODES) ? rowptr[idx] : NE;
    __syncthreads();
    const int bstart = rowptr[n0];
    const int bend = (b == NBUCKET - 1) ? NE : rowptr[n0 + 256];
    for (int e = bstart + tid; e < bend; e += 256) {
        int2 p = bpair[e];
        int slot = atomicAdd(&cur[p.y & 255], 1);
        ssrc[slot] = p.x;
    }
}

// ---------------- f32 -> bf16 conversions ----------------
__global__ __launch_bounds__(256) void k_cvt_x(const float* __restrict__ x, uint32_t* __restrict__ xb) {
    size_t i = (size_t)blockIdx.x * 256 + threadIdx.x;       // 4 elems each
    if (i * 4 >= (size_t)N_NODES * DIM) return;
    float4 v = *reinterpret_cast<const float4*>(x + i * 4);
    uint2 o;
    o.x = f2b_rne(v.x) | (f2b_rne(v.y) << 16);
    o.y = f2b_rne(v.z) | (f2b_rne(v.w) << 16);
    *reinterpret_cast<uint2*>(xb + i * 2) = o;
}

// wcat[n][0:128]=W_l[n][:], wcat[n][128:256]=W_r[n][:]  (bf16)
__global__ __launch_bounds__(256) void k_cvt_w(
    const float* __restrict__ W1l, const float* __restrict__ W1r,
    const float* __restrict__ W2l, const float* __restrict__ W2r,
    uint16_t* __restrict__ w1, uint16_t* __restrict__ w2) {
    int gid = blockIdx.x * 256 + threadIdx.x;                // 16384 total
    int layer = gid >> 13;
    int e = (gid & 8191) * 4;
    int row = e >> 8;
    int col = e & 255;
    const float* Wl = layer ? W2l : W1l;
    const float* Wr = layer ? W2r : W1r;
    const float* srcm = (col < 128) ? Wl : Wr;
    int c = col & 127;
    float4 v = *reinterpret_cast<const float4*>(&srcm[row * 128 + c]);
    uint2 o;
    o.x = f2b_rne(v.x) | (f2b_rne(v.y) << 16);
    o.y = f2b_rne(v.z) | (f2b_rne(v.w) << 16);
    uint16_t* wd = layer ? w2 : w1;
    *reinterpret_cast<uint2*>(&wd[row * 256 + col]) = o;
}

// ---------------- per-node mean aggregation (unroll-8 ILP, bf16) ----------
__global__ __launch_bounds__(256) void k_agg(const int* __restrict__ rowptr,
                                             const int* __restrict__ ssrc,
                                             const uint32_t* __restrict__ featb,
                                             uint32_t* __restrict__ meanb) {
    int node = (int)((blockIdx.x * 256 + threadIdx.x) >> 6);
    if (node >= N_NODES) return;
    int lane = threadIdx.x & 63;
    int start = rowptr[node];
    int end   = rowptr[node + 1];

    float ax0 = 0.f, ay0 = 0.f, ax1 = 0.f, ay1 = 0.f;
    float ax2 = 0.f, ay2 = 0.f, ax3 = 0.f, ay3 = 0.f;

    int e = start;
    for (; e + 8 <= end; e += 8) {
        int s0 = ssrc[e + 0], s1 = ssrc[e + 1], s2 = ssrc[e + 2], s3 = ssrc[e + 3];
        int s4 = ssrc[e + 4], s5 = ssrc[e + 5], s6 = ssrc[e + 6], s7 = ssrc[e + 7];
        uint32_t u0 = featb[(size_t)s0 * 64 + lane];
        uint32_t u1 = featb[(size_t)s1 * 64 + lane];
        uint32_t u2 = featb[(size_t)s2 * 64 + lane];
        uint32_t u3 = featb[(size_t)s3 * 64 + lane];
        uint32_t u4 = featb[(size_t)s4 * 64 + lane];
        uint32_t u5 = featb[(size_t)s5 * 64 + lane];
        uint32_t u6 = featb[(size_t)s6 * 64 + lane];
        uint32_t u7 = featb[(size_t)s7 * 64 + lane];
        ax0 += b2f_lo(u0); ay0 += b2f_hi(u0);
        ax1 += b2f_lo(u1); ay1 += b2f_hi(u1);
        ax2 += b2f_lo(u2); ay2 += b2f_hi(u2);
        ax3 += b2f_lo(u3); ay3 += b2f_hi(u3);
        ax0 += b2f_lo(u4); ay0 += b2f_hi(u4);
        ax1 += b2f_lo(u5); ay1 += b2f_hi(u5);
        ax2 += b2f_lo(u6); ay2 += b2f_hi(u6);
        ax3 += b2f_lo(u7); ay3 += b2f_hi(u7);
    }
    if (e + 4 <= end) {
        int s0 = ssrc[e + 0], s1 = ssrc[e + 1], s2 = ssrc[e + 2], s3 = ssrc[e + 3];
        uint32_t u0 = featb[(size_t)s0 * 64 + lane];
        uint32_t u1 = featb[(size_t)s1 * 64 + lane];
        uint32_t u2 = featb[(size_t)s2 * 64 + lane];
        uint32_t u3 = featb[(size_t)s3 * 64 + lane];
        ax0 += b2f_lo(u0); ay0 += b2f_hi(u0);
        ax1 += b2f_lo(u1); ay1 += b2f_hi(u1);
        ax2 += b2f_lo(u2); ay2 += b2f_hi(u2);
        ax3 += b2f_lo(u3); ay3 += b2f_hi(u3);
        e += 4;
    }
    for (; e < end; ++e) {
        int s = ssrc[e];
        uint32_t u = featb[(size_t)s * 64 + lane];
        ax0 += b2f_lo(u); ay0 += b2f_hi(u);
    }

    int cnt = end - start;
    float inv = cnt > 0 ? 1.0f / (float)cnt : 0.0f;
    float ax = ((ax0 + ax1) + (ax2 + ax3)) * inv;
    float ay = ((ay0 + ay1) + (ay2 + ay3)) * inv;
    meanb[(size_t)node * 64 + lane] = f2b_rne(ax) | (f2b_rne(ay) << 16);
}

// ---------------- MFMA SAGE layer (no LDS; B fragments from global/L1) ----
template <bool RELU, bool BF16_OUT>
__global__ __launch_bounds__(256) void k_layer(
    const uint16_t* __restrict__ meanb, const uint16_t* __restrict__ xb,
    const uint16_t* __restrict__ wcat, const float* __restrict__ bias,
    void* __restrict__ outp)
{
    const int tid = threadIdx.x;
    const int lane = tid & 63;
    const int w = tid >> 6;
    const int wm = (w >> 1) * 64, wn = (w & 1) * 64;
    const int lrow = lane & 31, lk = (lane >> 5) * 8;
    const int base = blockIdx.x * 128;

    f32x16 acc00, acc01, acc10, acc11;
#pragma unroll
    for (int r = 0; r < 16; ++r) { acc00[r] = 0.f; acc01[r] = 0.f; acc10[r] = 0.f; acc11[r] = 0.f; }

    int r0 = base + wm + lrow;
    int r1 = r0 + 32;
    if (r0 > N_NODES - 1) r0 = N_NODES - 1;
    if (r1 > N_NODES - 1) r1 = N_NODES - 1;
    const uint16_t* a0m = meanb + (size_t)r0 * DIM + lk;
    const uint16_t* a1m = meanb + (size_t)r1 * DIM + lk;
    const uint16_t* a0x = xb   + (size_t)r0 * DIM + lk;
    const uint16_t* a1x = xb   + (size_t)r1 * DIM + lk;
    const uint16_t* b0p = wcat + (size_t)(wn + lrow) * 256 + lk;
    const uint16_t* b1p = wcat + (size_t)(wn + 32 + lrow) * 256 + lk;

#pragma unroll
    for (int ks = 0; ks < 16; ++ks) {
        const int klocal = (ks & 7) * 16;
        bf16x8 a0 = *reinterpret_cast<const bf16x8*>(((ks < 8) ? a0m : a0x) + klocal);
        bf16x8 a1 = *reinterpret_cast<const bf16x8*>(((ks < 8) ? a1m : a1x) + klocal);
        bf16x8 b0 = *reinterpret_cast<const bf16x8*>(b0p + ks * 16);
        bf16x8 b1 = *reinterpret_cast<const bf16x8*>(b1p + ks * 16);
        acc00 = __builtin_amdgcn_mfma_f32_32x32x16_bf16(a0, b0, acc00, 0, 0, 0);
        acc01 = __builtin_amdgcn_mfma_f32_32x32x16_bf16(a0, b1, acc01, 0, 0, 0);
        acc10 = __builtin_amdgcn_mfma_f32_32x32x16_bf16(a1, b0, acc10, 0, 0, 0);
        acc11 = __builtin_amdgcn_mfma_f32_32x32x16_bf16(a1, b1, acc11, 0, 0, 0);
    }

    const float bc0 = bias[wn + lrow];
    const float bc1 = bias[wn + 32 + lrow];
    const int hi4 = 4 * (lane >> 5);

#define STORE_TILE(ACC, MI, NI, BB)                                            \
    {                                                                          \
        const int colg = wn + (NI) * 32 + lrow;                                \
        _Pragma("unroll")                                                      \
        for (int r = 0; r < 16; ++r) {                                         \
            int rowg = base + wm + (MI) * 32 + (r & 3) + 8 * (r >> 2) + hi4;   \
            if (rowg < N_NODES) {                                              \
                float v = ACC[r] + (BB);                                       \
                if (RELU) v = fmaxf(v, 0.0f);                                  \
                if (BF16_OUT)                                                  \
                    ((uint16_t*)outp)[(size_t)rowg * DIM + colg] =             \
                        (uint16_t)f2b_rne(v);                                  \
                else                                                           \
                    ((float*)outp)[(size_t)rowg * DIM + colg] = v;             \
            }                                                                  \
        }                                                                      \
    }
    STORE_TILE(acc00, 0, 0, bc0)
    STORE_TILE(acc01, 0, 1, bc1)
    STORE_TILE(acc10, 1, 0, bc0)
    STORE_TILE(acc11, 1, 1, bc1)
#undef STORE_TILE
}

extern "C" void kernel_launch(void* const* d_in, const int* in_sizes, int n_in,
                              void* d_out, int out_size, void* d_ws, size_t ws_size,
                              hipStream_t stream) {
    const float* x   = (const float*)d_in[0];
    const int*   ei  = (const int*)d_in[1];
    const float* W1l = (const float*)d_in[2];
    const float* W1r = (const float*)d_in[3];
    const float* b1  = (const float*)d_in[4];
    const float* W2l = (const float*)d_in[5];
    const float* W2r = (const float*)d_in[6];
    const float* b2  = (const float*)d_in[7];
    const int* src = ei;
    const int* dst = ei + NE;

    char* wsb = (char*)d_ws;
    int*      rowptr  = (int*)(wsb + ROW_B);
    int*      part    = (int*)(wsb + PART_B);
    int*      bcur    = (int*)(wsb + BCUR_B);
    int*      ssrc    = (int*)(wsb + SRC_B);
    uint32_t* xb32    = (uint32_t*)(wsb + XB_B);
    uint16_t* xb16    = (uint16_t*)(wsb + XB_B);
    uint32_t* hb32    = (uint32_t*)(wsb + HB_B);
    uint16_t* hb16    = (uint16_t*)(wsb + HB_B);
    uint32_t* mb32    = (uint32_t*)(wsb + MB_B);
    uint16_t* mb16    = (uint16_t*)(wsb + MB_B);
    uint16_t* w1      = (uint16_t*)(wsb + W1_B);
    uint16_t* w2      = (uint16_t*)(wsb + W2_B);
    int2*     bpair   = (int2*)(wsb + BPAIR_B);
    float*    outf    = (float*)d_out;

    hipMemsetAsync(rowptr, 0, (N_NODES + 1) * sizeof(int), stream);

    const int eb = (NE + 255) / 256;
    k_hist <<<eb, 256, 0, stream>>>(dst, rowptr);
    k_scan1<<<SCAN_NB, SCAN_B, 0, stream>>>(rowptr, part);
    k_scan2<<<1, 128, 0, stream>>>(part, rowptr);
    k_scan3<<<SCAN_NB, SCAN_B, 0, stream>>>(rowptr, part);
    k_binit<<<2, 256, 0, stream>>>(rowptr, bcur);
    k_bucket<<<BK_WG, 1024, 0, stream>>>(src, dst, bcur, bpair);
    k_sortb<<<NBUCKET, 256, 0, stream>>>(rowptr, bpair, ssrc);

    k_cvt_x<<<12500, 256, 0, stream>>>(x, xb32);
    k_cvt_w<<<64, 256, 0, stream>>>(W1l, W1r, W2l, W2r, w1, w2);

    const int agg_blocks = N_NODES / 4;            // one wave per node
    const int layer_blocks = (N_NODES + 127) / 128;

    // layer 1
    k_agg<<<agg_blocks, 256, 0, stream>>>(rowptr, ssrc, xb32, mb32);
    k_layer<true, true><<<layer_blocks, 256, 0, stream>>>(mb16, xb16, w1, b1, (void*)hb16);

    // layer 2
    k_agg<<<agg_blocks, 256, 0, stream>>>(rowptr, ssrc, hb32, mb32);
    k_layer<false, false><<<layer_blocks, 256, 0, stream>>>(mb16, hb16, w2, b2, (void*)outf);
}

// Round 10
// 380.269 us; speedup vs baseline: 15.1102x; 1.1442x over previous
//
#include <hip/hip_runtime.h>
#include <stdint.h>

#define N_NODES 100000
#define NE      1600000
#define DIM     128
#define NBUCKET 391                  // ceil(N/256)

typedef __attribute__((ext_vector_type(8)))  __bf16 bf16x8;
typedef __attribute__((ext_vector_type(16))) float  f32x16;

// ---- ws byte offsets ----
#define ROW_B   0u           // rowptr: (N+1) ints (written by k_sortb)
#define BHIST_B 401408u      // bucket histogram: 392 ints
#define BBASE_B 403456u      // bucket bases: 392 ints
#define BCUR_B  405504u      // bucket cursors: 392 ints
#define SRC_B   409600u      // sorted_src: NE ints
#define XB_B    6809600u     // x  bf16: N*128
#define HB_B    32409600u    // h  bf16: N*128
#define MB_B    58009600u    // mean bf16: N*128
#define W1_B    83609600u    // wcat1 bf16: 128*256
#define W2_B    83675136u    // wcat2 bf16: 128*256
#define BPAIR_B 83740672u    // (src,dst) records: NE int2 = 12.8MB -> end ~96.5MB

// ---------------- helpers ----------------
__device__ __forceinline__ uint32_t f2b_rne(float f) {
    uint32_t u = __float_as_uint(f);
    return (u + 0x7FFFu + ((u >> 16) & 1u)) >> 16;
}
__device__ __forceinline__ float b2f_lo(uint32_t u) { return __uint_as_float(u << 16); }
__device__ __forceinline__ float b2f_hi(uint32_t u) { return __uint_as_float(u & 0xFFFF0000u); }

#define BK_WG   512
#define BK_EPW  3125          // NE / BK_WG

// ---------------- bucket histogram (LDS-aggregated) ----------------
__global__ __launch_bounds__(1024) void k_bhist(const int* __restrict__ dst,
                                                int* __restrict__ bhist) {
    __shared__ int h[392];
    const int tid = threadIdx.x;
    if (tid < 392) h[tid] = 0;
    __syncthreads();
    const int e0 = blockIdx.x * BK_EPW;
    const int e1 = e0 + BK_EPW;
    for (int e = e0 + tid; e < e1; e += 1024)
        atomicAdd(&h[dst[e] >> 8], 1);
    __syncthreads();
    if (tid < 392) {
        int v = h[tid];
        if (v) atomicAdd(&bhist[tid], v);
    }
}

// ---------------- bucket scan (one wg) ----------------
__global__ __launch_bounds__(512) void k_bscan(const int* __restrict__ bhist,
                                               int* __restrict__ bbase,
                                               int* __restrict__ bcur) {
    __shared__ int sm[512];
    const int tid = threadIdx.x;
    int v = (tid < NBUCKET) ? bhist[tid] : 0;
    sm[tid] = v;
    __syncthreads();
    for (int off = 1; off < 512; off <<= 1) {
        int t = (tid >= off) ? sm[tid - off] : 0;
        __syncthreads();
        sm[tid] += t;
        __syncthreads();
    }
    int ex = sm[tid] - v;
    if (tid <= NBUCKET) bbase[tid] = ex;      // bbase[NBUCKET] == NE
    if (tid < NBUCKET) bcur[tid] = ex;
}

// ---------------- phase A: bucket edges by dst>>8 (dense 8B writes) ------
__global__ __launch_bounds__(1024) void k_bucket(
    const int* __restrict__ src, const int* __restrict__ dst,
    int* __restrict__ bcur, int2* __restrict__ bpair) {
    __shared__ int hist[392];
    __shared__ int base[392];
    __shared__ int cur[392];
    const int tid = threadIdx.x;
    const int e0 = blockIdx.x * BK_EPW;
    const int e1 = e0 + BK_EPW;

    if (tid < 392) { hist[tid] = 0; cur[tid] = 0; }
    __syncthreads();
    for (int e = e0 + tid; e < e1; e += 1024)
        atomicAdd(&hist[dst[e] >> 8], 1);
    __syncthreads();
    if (tid < 392) {
        int h = hist[tid];
        base[tid] = h ? atomicAdd(&bcur[tid], h) : 0;
    }
    __syncthreads();
    for (int e = e0 + tid; e < e1; e += 1024) {
        int d = dst[e];
        int b = d >> 8;
        int loc = atomicAdd(&cur[b], 1);
        bpair[(size_t)(base[b] + loc)] = make_int2(src[e], d);
    }
}

// ---------------- phase B: per-bucket degree + scan + place --------------
__global__ __launch_bounds__(256) void k_sortb(
    const int* __restrict__ bbase, const int2* __restrict__ bpair,
    int* __restrict__ rowptr, int* __restrict__ ssrc) {
    __shared__ int deg[256];
    __shared__ int sm[256];
    __shared__ int cur[256];
    const int b = blockIdx.x;
    const int tid = threadIdx.x;
    const int n0 = b << 8;
    const int bstart = bbase[b];
    const int bend   = bbase[b + 1];

    deg[tid] = 0;
    __syncthreads();
    for (int e = bstart + tid; e < bend; e += 256)
        atomicAdd(&deg[bpair[e].y & 255], 1);
    __syncthreads();
    int v = deg[tid];
    sm[tid] = v;
    __syncthreads();
    for (int off = 1; off < 256; off <<= 1) {
        int t = (tid >= off) ? sm[tid - off] : 0;
        __syncthreads();
        sm[tid] += t;
        __syncthreads();
    }
    int ex = sm[tid] - v;
    int idx = n0 + tid;
    if (idx <= N_NODES) rowptr[idx] = bstart + ex;   // last bucket tid=160 writes rowptr[N]=NE
    cur[tid] = bstart + ex;
    __syncthreads();
    for (int e = bstart + tid; e < bend; e += 256) {
        int2 p = bpair[e];
        int slot = atomicAdd(&cur[p.y & 255], 1);
        ssrc[slot] = p.x;
    }
}

// ---------------- f32 -> bf16 conversions ----------------
__global__ __launch_bounds__(256) void k_cvt_x(const float* __restrict__ x, uint32_t* __restrict__ xb) {
    size_t i = (size_t)blockIdx.x * 256 + threadIdx.x;       // 4 elems each
    if (i * 4 >= (size_t)N_NODES * DIM) return;
    float4 v = *reinterpret_cast<const float4*>(x + i * 4);
    uint2 o;
    o.x = f2b_rne(v.x) | (f2b_rne(v.y) << 16);
    o.y = f2b_rne(v.z) | (f2b_rne(v.w) << 16);
    *reinterpret_cast<uint2*>(xb + i * 2) = o;
}

// wcat[n][0:128]=W_l[n][:], wcat[n][128:256]=W_r[n][:]  (bf16)
__global__ __launch_bounds__(256) void k_cvt_w(
    const float* __restrict__ W1l, const float* __restrict__ W1r,
    const float* __restrict__ W2l, const float* __restrict__ W2r,
    uint16_t* __restrict__ w1, uint16_t* __restrict__ w2) {
    int gid = blockIdx.x * 256 + threadIdx.x;                // 16384 total
    int layer = gid >> 13;
    int e = (gid & 8191) * 4;
    int row = e >> 8;
    int col = e & 255;
    const float* Wl = layer ? W2l : W1l;
    const float* Wr = layer ? W2r : W1r;
    const float* srcm = (col < 128) ? Wl : Wr;
    int c = col & 127;
    float4 v = *reinterpret_cast<const float4*>(&srcm[row * 128 + c]);
    uint2 o;
    o.x = f2b_rne(v.x) | (f2b_rne(v.y) << 16);
    o.y = f2b_rne(v.z) | (f2b_rne(v.w) << 16);
    uint16_t* wd = layer ? w2 : w1;
    *reinterpret_cast<uint2*>(&wd[row * 256 + col]) = o;
}

// ---------------- per-node mean aggregation (unroll-8 ILP, bf16) ----------
__global__ __launch_bounds__(256) void k_agg(const int* __restrict__ rowptr,
                                             const int* __restrict__ ssrc,
                                             const uint32_t* __restrict__ featb,
                                             uint32_t* __restrict__ meanb) {
    int node = (int)((blockIdx.x * 256 + threadIdx.x) >> 6);
    if (node >= N_NODES) return;
    int lane = threadIdx.x & 63;
    int start = rowptr[node];
    int end   = rowptr[node + 1];

    float ax0 = 0.f, ay0 = 0.f, ax1 = 0.f, ay1 = 0.f;
    float ax2 = 0.f, ay2 = 0.f, ax3 = 0.f, ay3 = 0.f;

    int e = start;
    for (; e + 8 <= end; e += 8) {
        int s0 = ssrc[e + 0], s1 = ssrc[e + 1], s2 = ssrc[e + 2], s3 = ssrc[e + 3];
        int s4 = ssrc[e + 4], s5 = ssrc[e + 5], s6 = ssrc[e + 6], s7 = ssrc[e + 7];
        uint32_t u0 = featb[(size_t)s0 * 64 + lane];
        uint32_t u1 = featb[(size_t)s1 * 64 + lane];
        uint32_t u2 = featb[(size_t)s2 * 64 + lane];
        uint32_t u3 = featb[(size_t)s3 * 64 + lane];
        uint32_t u4 = featb[(size_t)s4 * 64 + lane];
        uint32_t u5 = featb[(size_t)s5 * 64 + lane];
        uint32_t u6 = featb[(size_t)s6 * 64 + lane];
        uint32_t u7 = featb[(size_t)s7 * 64 + lane];
        ax0 += b2f_lo(u0); ay0 += b2f_hi(u0);
        ax1 += b2f_lo(u1); ay1 += b2f_hi(u1);
        ax2 += b2f_lo(u2); ay2 += b2f_hi(u2);
        ax3 += b2f_lo(u3); ay3 += b2f_hi(u3);
        ax0 += b2f_lo(u4); ay0 += b2f_hi(u4);
        ax1 += b2f_lo(u5); ay1 += b2f_hi(u5);
        ax2 += b2f_lo(u6); ay2 += b2f_hi(u6);
        ax3 += b2f_lo(u7); ay3 += b2f_hi(u7);
    }
    if (e + 4 <= end) {
        int s0 = ssrc[e + 0], s1 = ssrc[e + 1], s2 = ssrc[e + 2], s3 = ssrc[e + 3];
        uint32_t u0 = featb[(size_t)s0 * 64 + lane];
        uint32_t u1 = featb[(size_t)s1 * 64 + lane];
        uint32_t u2 = featb[(size_t)s2 * 64 + lane];
        uint32_t u3 = featb[(size_t)s3 * 64 + lane];
        ax0 += b2f_lo(u0); ay0 += b2f_hi(u0);
        ax1 += b2f_lo(u1); ay1 += b2f_hi(u1);
        ax2 += b2f_lo(u2); ay2 += b2f_hi(u2);
        ax3 += b2f_lo(u3); ay3 += b2f_hi(u3);
        e += 4;
    }
    for (; e < end; ++e) {
        int s = ssrc[e];
        uint32_t u = featb[(size_t)s * 64 + lane];
        ax0 += b2f_lo(u); ay0 += b2f_hi(u);
    }

    int cnt = end - start;
    float inv = cnt > 0 ? 1.0f / (float)cnt : 0.0f;
    float ax = ((ax0 + ax1) + (ax2 + ax3)) * inv;
    float ay = ((ay0 + ay1) + (ay2 + ay3)) * inv;
    meanb[(size_t)node * 64 + lane] = f2b_rne(ax) | (f2b_rne(ay) << 16);
}

// ---------------- MFMA SAGE layer (no LDS; B fragments from global/L1) ----
template <bool RELU, bool BF16_OUT>
__global__ __launch_bounds__(256) void k_layer(
    const uint16_t* __restrict__ meanb, const uint16_t* __restrict__ xb,
    const uint16_t* __restrict__ wcat, const float* __restrict__ bias,
    void* __restrict__ outp)
{
    const int tid = threadIdx.x;
    const int lane = tid & 63;
    const int w = tid >> 6;
    const int wm = (w >> 1) * 64, wn = (w & 1) * 64;
    const int lrow = lane & 31, lk = (lane >> 5) * 8;
    const int base = blockIdx.x * 128;

    f32x16 acc00, acc01, acc10, acc11;
#pragma unroll
    for (int r = 0; r < 16; ++r) { acc00[r] = 0.f; acc01[r] = 0.f; acc10[r] = 0.f; acc11[r] = 0.f; }

    int r0 = base + wm + lrow;
    int r1 = r0 + 32;
    if (r0 > N_NODES - 1) r0 = N_NODES - 1;
    if (r1 > N_NODES - 1) r1 = N_NODES - 1;
    const uint16_t* a0m = meanb + (size_t)r0 * DIM + lk;
    const uint16_t* a1m = meanb + (size_t)r1 * DIM + lk;
    const uint16_t* a0x = xb   + (size_t)r0 * DIM + lk;
    const uint16_t* a1x = xb   + (size_t)r1 * DIM + lk;
    const uint16_t* b0p = wcat + (size_t)(wn + lrow) * 256 + lk;
    const uint16_t* b1p = wcat + (size_t)(wn + 32 + lrow) * 256 + lk;

#pragma unroll
    for (int ks = 0; ks < 16; ++ks) {
        const int klocal = (ks & 7) * 16;
        bf16x8 a0 = *reinterpret_cast<const bf16x8*>(((ks < 8) ? a0m : a0x) + klocal);
        bf16x8 a1 = *reinterpret_cast<const bf16x8*>(((ks < 8) ? a1m : a1x) + klocal);
        bf16x8 b0 = *reinterpret_cast<const bf16x8*>(b0p + ks * 16);
        bf16x8 b1 = *reinterpret_cast<const bf16x8*>(b1p + ks * 16);
        acc00 = __builtin_amdgcn_mfma_f32_32x32x16_bf16(a0, b0, acc00, 0, 0, 0);
        acc01 = __builtin_amdgcn_mfma_f32_32x32x16_bf16(a0, b1, acc01, 0, 0, 0);
        acc10 = __builtin_amdgcn_mfma_f32_32x32x16_bf16(a1, b0, acc10, 0, 0, 0);
        acc11 = __builtin_amdgcn_mfma_f32_32x32x16_bf16(a1, b1, acc11, 0, 0, 0);
    }

    const float bc0 = bias[wn + lrow];
    const float bc1 = bias[wn + 32 + lrow];
    const int hi4 = 4 * (lane >> 5);

#define STORE_TILE(ACC, MI, NI, BB)                                            \
    {                                                                          \
        const int colg = wn + (NI) * 32 + lrow;                                \
        _Pragma("unroll")                                                      \
        for (int r = 0; r < 16; ++r) {                                         \
            int rowg = base + wm + (MI) * 32 + (r & 3) + 8 * (r >> 2) + hi4;   \
            if (rowg < N_NODES) {                                              \
                float v = ACC[r] + (BB);                                       \
                if (RELU) v = fmaxf(v, 0.0f);                                  \
                if (BF16_OUT)                                                  \
                    ((uint16_t*)outp)[(size_t)rowg * DIM + colg] =             \
                        (uint16_t)f2b_rne(v);                                  \
                else                                                           \
                    ((float*)outp)[(size_t)rowg * DIM + colg] = v;             \
            }                                                                  \
        }                                                                      \
    }
    STORE_TILE(acc00, 0, 0, bc0)
    STORE_TILE(acc01, 0, 1, bc1)
    STORE_TILE(acc10, 1, 0, bc0)
    STORE_TILE(acc11, 1, 1, bc1)
#undef STORE_TILE
}

extern "C" void kernel_launch(void* const* d_in, const int* in_sizes, int n_in,
                              void* d_out, int out_size, void* d_ws, size_t ws_size,
                              hipStream_t stream) {
    const float* x   = (const float*)d_in[0];
    const int*   ei  = (const int*)d_in[1];
    const float* W1l = (const float*)d_in[2];
    const float* W1r = (const float*)d_in[3];
    const float* b1  = (const float*)d_in[4];
    const float* W2l = (const float*)d_in[5];
    const float* W2r = (const float*)d_in[6];
    const float* b2  = (const float*)d_in[7];
    const int* src = ei;
    const int* dst = ei + NE;

    char* wsb = (char*)d_ws;
    int*      rowptr  = (int*)(wsb + ROW_B);
    int*      bhist   = (int*)(wsb + BHIST_B);
    int*      bbase   = (int*)(wsb + BBASE_B);
    int*      bcur    = (int*)(wsb + BCUR_B);
    int*      ssrc    = (int*)(wsb + SRC_B);
    uint32_t* xb32    = (uint32_t*)(wsb + XB_B);
    uint16_t* xb16    = (uint16_t*)(wsb + XB_B);
    uint32_t* hb32    = (uint32_t*)(wsb + HB_B);
    uint16_t* hb16    = (uint16_t*)(wsb + HB_B);
    uint32_t* mb32    = (uint32_t*)(wsb + MB_B);
    uint16_t* mb16    = (uint16_t*)(wsb + MB_B);
    uint16_t* w1      = (uint16_t*)(wsb + W1_B);
    uint16_t* w2      = (uint16_t*)(wsb + W2_B);
    int2*     bpair   = (int2*)(wsb + BPAIR_B);
    float*    outf    = (float*)d_out;

    hipMemsetAsync(bhist, 0, 392 * sizeof(int), stream);

    k_bhist <<<BK_WG, 1024, 0, stream>>>(dst, bhist);
    k_bscan <<<1, 512, 0, stream>>>(bhist, bbase, bcur);
    k_bucket<<<BK_WG, 1024, 0, stream>>>(src, dst, bcur, bpair);
    k_sortb <<<NBUCKET, 256, 0, stream>>>(bbase, bpair, rowptr, ssrc);

    k_cvt_x<<<12500, 256, 0, stream>>>(x, xb32);
    k_cvt_w<<<64, 256, 0, stream>>>(W1l, W1r, W2l, W2r, w1, w2);

    const int agg_blocks = N_NODES / 4;            // one wave per node
    const int layer_blocks = (N_NODES + 127) / 128;

    // layer 1
    k_agg<<<agg_blocks, 256, 0, stream>>>(rowptr, ssrc, xb32, mb32);
    k_layer<true, true><<<layer_blocks, 256, 0, stream>>>(mb16, xb16, w1, b1, (void*)hb16);

    // layer 2
    k_agg<<<agg_blocks, 256, 0, stream>>>(rowptr, ssrc, hb32, mb32);
    k_layer<false, false><<<layer_blocks, 256, 0, stream>>>(mb16, hb16, w2, b2, (void*)outf);
}

// Round 12
// 368.267 us; speedup vs baseline: 15.6026x; 1.0326x over previous
//
#include <hip/hip_runtime.h>
#include <stdint.h>

#define N_NODES 100000
#define NE      1600000
#define DIM     128
#define NBUCKET 391                  // ceil(N/256)

typedef __attribute__((ext_vector_type(8)))  __bf16 bf16x8;
typedef __attribute__((ext_vector_type(16))) float  f32x16;

// ---- ws byte offsets ----
#define ROW_B   0u           // rowptr: (N+1) ints (written by k_sortb)
#define BHIST_B 401408u      // bucket histogram: 392 ints
#define BBASE_B 403456u      // bucket bases: 392 ints
#define BCUR_B  405504u      // bucket cursors: 392 ints
#define SRC_B   409600u      // sorted_src: NE ints
#define XB_B    6809600u     // x  bf16: N*128
#define HB_B    32409600u    // h  bf16: N*128
#define MB_B    58009600u    // mean bf16: N*128
#define W1_B    83609600u    // wcat1 bf16: 128*256
#define W2_B    83675136u    // wcat2 bf16: 128*256
#define BPAIR_B 83740672u    // packed (src<<8|dst&255): NE uint32 = 6.4MB

// ---------------- helpers ----------------
__device__ __forceinline__ uint32_t f2b_rne(float f) {
    uint32_t u = __float_as_uint(f);
    return (u + 0x7FFFu + ((u >> 16) & 1u)) >> 16;
}
__device__ __forceinline__ float b2f_lo(uint32_t u) { return __uint_as_float(u << 16); }
__device__ __forceinline__ float b2f_hi(uint32_t u) { return __uint_as_float(u & 0xFFFF0000u); }

#define BK_WG   512
#define BK_EPW  3125          // NE / BK_WG

// ---------------- bucket histogram (LDS-aggregated) ----------------
__global__ __launch_bounds__(1024) void k_bhist(const int* __restrict__ dst,
                                                int* __restrict__ bhist) {
    __shared__ int h[392];
    const int tid = threadIdx.x;
    if (tid < 392) h[tid] = 0;
    __syncthreads();
    const int e0 = blockIdx.x * BK_EPW;
    const int e1 = e0 + BK_EPW;
    for (int e = e0 + tid; e < e1; e += 1024)
        atomicAdd(&h[dst[e] >> 8], 1);
    __syncthreads();
    if (tid < 392) {
        int v = h[tid];
        if (v) atomicAdd(&bhist[tid], v);
    }
}

// ---------------- bucket scan (one wg) ----------------
__global__ __launch_bounds__(512) void k_bscan(const int* __restrict__ bhist,
                                               int* __restrict__ bbase,
                                               int* __restrict__ bcur) {
    __shared__ int sm[512];
    const int tid = threadIdx.x;
    int v = (tid < NBUCKET) ? bhist[tid] : 0;
    sm[tid] = v;
    __syncthreads();
    for (int off = 1; off < 512; off <<= 1) {
        int t = (tid >= off) ? sm[tid - off] : 0;
        __syncthreads();
        sm[tid] += t;
        __syncthreads();
    }
    int ex = sm[tid] - v;
    if (tid <= NBUCKET) bbase[tid] = ex;      // bbase[NBUCKET] == NE
    if (tid < NBUCKET) bcur[tid] = ex;
}

// ---------------- phase A: bucket edges by dst>>8 (dense 4B writes) ------
__global__ __launch_bounds__(1024) void k_bucket(
    const int* __restrict__ src, const int* __restrict__ dst,
    int* __restrict__ bcur, uint32_t* __restrict__ bpair) {
    __shared__ int hist[392];
    __shared__ int base[392];
    __shared__ int cur[392];
    const int tid = threadIdx.x;
    const int e0 = blockIdx.x * BK_EPW;
    const int e1 = e0 + BK_EPW;

    if (tid < 392) { hist[tid] = 0; cur[tid] = 0; }
    __syncthreads();
    for (int e = e0 + tid; e < e1; e += 1024)
        atomicAdd(&hist[dst[e] >> 8], 1);
    __syncthreads();
    if (tid < 392) {
        int h = hist[tid];
        base[tid] = h ? atomicAdd(&bcur[tid], h) : 0;
    }
    __syncthreads();
    for (int e = e0 + tid; e < e1; e += 1024) {
        int d = dst[e];
        int b = d >> 8;
        int loc = atomicAdd(&cur[b], 1);
        bpair[(size_t)(base[b] + loc)] = ((uint32_t)src[e] << 8) | (uint32_t)(d & 255);
    }
}

// ---------------- phase B: per-bucket degree + scan + place --------------
__global__ __launch_bounds__(256) void k_sortb(
    const int* __restrict__ bbase, const uint32_t* __restrict__ bpair,
    int* __restrict__ rowptr, int* __restrict__ ssrc) {
    __shared__ int deg[256];
    __shared__ int sm[256];
    __shared__ int cur[256];
    const int b = blockIdx.x;
    const int tid = threadIdx.x;
    const int n0 = b << 8;
    const int bstart = bbase[b];
    const int bend   = bbase[b + 1];

    deg[tid] = 0;
    __syncthreads();
    for (int e = bstart + tid; e < bend; e += 256)
        atomicAdd(&deg[bpair[e] & 255u], 1);
    __syncthreads();
    int v = deg[tid];
    sm[tid] = v;
    __syncthreads();
    for (int off = 1; off < 256; off <<= 1) {
        int t = (tid >= off) ? sm[tid - off] : 0;
        __syncthreads();
        sm[tid] += t;
        __syncthreads();
    }
    int ex = sm[tid] - v;
    int idx = n0 + tid;
    if (idx <= N_NODES) rowptr[idx] = bstart + ex;
    cur[tid] = bstart + ex;
    __syncthreads();
    for (int e = bstart + tid; e < bend; e += 256) {
        uint32_t p = bpair[e];
        int slot = atomicAdd(&cur[p & 255u], 1);
        ssrc[slot] = (int)(p >> 8);
    }
}

// ---------------- f32 -> bf16 conversions ----------------
__global__ __launch_bounds__(256) void k_cvt_x(const float* __restrict__ x, uint32_t* __restrict__ xb) {
    size_t i = (size_t)blockIdx.x * 256 + threadIdx.x;       // 4 elems each
    if (i * 4 >= (size_t)N_NODES * DIM) return;
    float4 v = *reinterpret_cast<const float4*>(x + i * 4);
    uint2 o;
    o.x = f2b_rne(v.x) | (f2b_rne(v.y) << 16);
    o.y = f2b_rne(v.z) | (f2b_rne(v.w) << 16);
    *reinterpret_cast<uint2*>(xb + i * 2) = o;
}

// wcat[n][0:128]=W_l[n][:], wcat[n][128:256]=W_r[n][:]  (bf16)
__global__ __launch_bounds__(256) void k_cvt_w(
    const float* __restrict__ W1l, const float* __restrict__ W1r,
    const float* __restrict__ W2l, const float* __restrict__ W2r,
    uint16_t* __restrict__ w1, uint16_t* __restrict__ w2) {
    int gid = blockIdx.x * 256 + threadIdx.x;                // 16384 total
    int layer = gid >> 13;
    int e = (gid & 8191) * 4;
    int row = e >> 8;
    int col = e & 255;
    const float* Wl = layer ? W2l : W1l;
    const float* Wr = layer ? W2r : W1r;
    const float* srcm = (col < 128) ? Wl : Wr;
    int c = col & 127;
    float4 v = *reinterpret_cast<const float4*>(&srcm[row * 128 + c]);
    uint2 o;
    o.x = f2b_rne(v.x) | (f2b_rne(v.y) << 16);
    o.y = f2b_rne(v.z) | (f2b_rne(v.w) << 16);
    uint16_t* wd = layer ? w2 : w1;
    *reinterpret_cast<uint2*>(&wd[row * 256 + col]) = o;
}

// ---------------- per-node mean aggregation (unroll-16 ILP, bf16) --------
__global__ __launch_bounds__(256) void k_agg(const int* __restrict__ rowptr,
                                             const int* __restrict__ ssrc,
                                             const uint32_t* __restrict__ featb,
                                             uint32_t* __restrict__ meanb) {
    int node = (int)((blockIdx.x * 256 + threadIdx.x) >> 6);
    if (node >= N_NODES) return;
    int lane = threadIdx.x & 63;
    int start = rowptr[node];
    int end   = rowptr[node + 1];

    float ax0 = 0.f, ay0 = 0.f, ax1 = 0.f, ay1 = 0.f;
    float ax2 = 0.f, ay2 = 0.f, ax3 = 0.f, ay3 = 0.f;

    int e = start;
    for (; e + 16 <= end; e += 16) {
        int s[16];
#pragma unroll
        for (int j = 0; j < 16; ++j) s[j] = ssrc[e + j];
        uint32_t u[16];
#pragma unroll
        for (int j = 0; j < 16; ++j) u[j] = featb[(size_t)s[j] * 64 + lane];
#pragma unroll
        for (int j = 0; j < 16; j += 4) {
            ax0 += b2f_lo(u[j + 0]); ay0 += b2f_hi(u[j + 0]);
            ax1 += b2f_lo(u[j + 1]); ay1 += b2f_hi(u[j + 1]);
            ax2 += b2f_lo(u[j + 2]); ay2 += b2f_hi(u[j + 2]);
            ax3 += b2f_lo(u[j + 3]); ay3 += b2f_hi(u[j + 3]);
        }
    }
    if (e + 8 <= end) {
        int s0 = ssrc[e + 0], s1 = ssrc[e + 1], s2 = ssrc[e + 2], s3 = ssrc[e + 3];
        int s4 = ssrc[e + 4], s5 = ssrc[e + 5], s6 = ssrc[e + 6], s7 = ssrc[e + 7];
        uint32_t u0 = featb[(size_t)s0 * 64 + lane];
        uint32_t u1 = featb[(size_t)s1 * 64 + lane];
        uint32_t u2 = featb[(size_t)s2 * 64 + lane];
        uint32_t u3 = featb[(size_t)s3 * 64 + lane];
        uint32_t u4 = featb[(size_t)s4 * 64 + lane];
        uint32_t u5 = featb[(size_t)s5 * 64 + lane];
        uint32_t u6 = featb[(size_t)s6 * 64 + lane];
        uint32_t u7 = featb[(size_t)s7 * 64 + lane];
        ax0 += b2f_lo(u0); ay0 += b2f_hi(u0);
        ax1 += b2f_lo(u1); ay1 += b2f_hi(u1);
        ax2 += b2f_lo(u2); ay2 += b2f_hi(u2);
        ax3 += b2f_lo(u3); ay3 += b2f_hi(u3);
        ax0 += b2f_lo(u4); ay0 += b2f_hi(u4);
        ax1 += b2f_lo(u5); ay1 += b2f_hi(u5);
        ax2 += b2f_lo(u6); ay2 += b2f_hi(u6);
        ax3 += b2f_lo(u7); ay3 += b2f_hi(u7);
        e += 8;
    }
    if (e + 4 <= end) {
        int s0 = ssrc[e + 0], s1 = ssrc[e + 1], s2 = ssrc[e + 2], s3 = ssrc[e + 3];
        uint32_t u0 = featb[(size_t)s0 * 64 + lane];
        uint32_t u1 = featb[(size_t)s1 * 64 + lane];
        uint32_t u2 = featb[(size_t)s2 * 64 + lane];
        uint32_t u3 = featb[(size_t)s3 * 64 + lane];
        ax0 += b2f_lo(u0); ay0 += b2f_hi(u0);
        ax1 += b2f_lo(u1); ay1 += b2f_hi(u1);
        ax2 += b2f_lo(u2); ay2 += b2f_hi(u2);
        ax3 += b2f_lo(u3); ay3 += b2f_hi(u3);
        e += 4;
    }
    for (; e < end; ++e) {
        int s = ssrc[e];
        uint32_t u = featb[(size_t)s * 64 + lane];
        ax0 += b2f_lo(u); ay0 += b2f_hi(u);
    }

    int cnt = end - start;
    float inv = cnt > 0 ? 1.0f / (float)cnt : 0.0f;
    float ax = ((ax0 + ax1) + (ax2 + ax3)) * inv;
    float ay = ((ay0 + ay1) + (ay2 + ay3)) * inv;
    meanb[(size_t)node * 64 + lane] = f2b_rne(ax) | (f2b_rne(ay) << 16);
}

// ---------------- MFMA SAGE layer (LDS-staged B, XOR-swizzled) -----------
// Two phases: stage wcat cols [0,128) (mean half), compute; then cols
// [128,256) (x half), compute. LDS 32 KB. Swizzle: ushort col ^ ((row&7)<<3)
// (16B granules preserved; read applies same XOR).
template <bool RELU, bool BF16_OUT>
__global__ __launch_bounds__(256) void k_layer(
    const uint16_t* __restrict__ meanb, const uint16_t* __restrict__ xb,
    const uint16_t* __restrict__ wcat, const float* __restrict__ bias,
    void* __restrict__ outp)
{
    __shared__ uint16_t Bs[128 * 128];   // 32 KB

    const int tid = threadIdx.x;
    const int lane = tid & 63;
    const int w = tid >> 6;
    const int wm = (w >> 1) * 64, wn = (w & 1) * 64;
    const int lrow = lane & 31, lk = (lane >> 5) * 8;
    const int base = blockIdx.x * 128;

    f32x16 acc00, acc01, acc10, acc11;
#pragma unroll
    for (int r = 0; r < 16; ++r) { acc00[r] = 0.f; acc01[r] = 0.f; acc10[r] = 0.f; acc11[r] = 0.f; }

    int r0 = base + wm + lrow;
    int r1 = r0 + 32;
    if (r0 > N_NODES - 1) r0 = N_NODES - 1;
    if (r1 > N_NODES - 1) r1 = N_NODES - 1;
    const uint16_t* a0m = meanb + (size_t)r0 * DIM + lk;
    const uint16_t* a1m = meanb + (size_t)r1 * DIM + lk;
    const uint16_t* a0x = xb   + (size_t)r0 * DIM + lk;
    const uint16_t* a1x = xb   + (size_t)r1 * DIM + lk;

    // staging role: thread t copies 8 granules of row srow, half shalf
    const int srow = tid >> 1, shalf = tid & 1;
    const int sx = (srow & 7) << 3;                     // ushort XOR, mult of 8
    const uint16_t* wsrc = wcat + srow * 256 + shalf * 64;
    uint16_t* wdst = Bs + srow * 128;

    // read role
    const int rx = ((wn + lrow) & 7) << 3;              // (wn+32+lrow)&7 == (wn+lrow)&7
    const uint16_t* bsp0 = Bs + (wn + lrow) * 128;
    const uint16_t* bsp1 = Bs + (wn + 32 + lrow) * 128;

    // ---- phase 1: mean half (wcat cols 0..127) ----
#pragma unroll
    for (int g = 0; g < 8; ++g) {
        int c = shalf * 64 + g * 8;
        *reinterpret_cast<uint4*>(wdst + (c ^ sx)) =
            *reinterpret_cast<const uint4*>(wsrc + g * 8);
    }
    __syncthreads();
#pragma unroll
    for (int ks = 0; ks < 8; ++ks) {
        const int klocal = ks * 16;
        bf16x8 a0 = *reinterpret_cast<const bf16x8*>(a0m + klocal);
        bf16x8 a1 = *reinterpret_cast<const bf16x8*>(a1m + klocal);
        bf16x8 b0 = *reinterpret_cast<const bf16x8*>(bsp0 + ((klocal + lk) ^ rx));
        bf16x8 b1 = *reinterpret_cast<const bf16x8*>(bsp1 + ((klocal + lk) ^ rx));
        acc00 = __builtin_amdgcn_mfma_f32_32x32x16_bf16(a0, b0, acc00, 0, 0, 0);
        acc01 = __builtin_amdgcn_mfma_f32_32x32x16_bf16(a0, b1, acc01, 0, 0, 0);
        acc10 = __builtin_amdgcn_mfma_f32_32x32x16_bf16(a1, b0, acc10, 0, 0, 0);
        acc11 = __builtin_amdgcn_mfma_f32_32x32x16_bf16(a1, b1, acc11, 0, 0, 0);
    }
    __syncthreads();
    // ---- phase 2: x half (wcat cols 128..255) ----
#pragma unroll
    for (int g = 0; g < 8; ++g) {
        int c = shalf * 64 + g * 8;
        *reinterpret_cast<uint4*>(wdst + (c ^ sx)) =
            *reinterpret_cast<const uint4*>(wsrc + 128 + g * 8);
    }
    __syncthreads();
#pragma unroll
    for (int ks = 0; ks < 8; ++ks) {
        const int klocal = ks * 16;
        bf16x8 a0 = *reinterpret_cast<const bf16x8*>(a0x + klocal);
        bf16x8 a1 = *reinterpret_cast<const bf16x8*>(a1x + klocal);
        bf16x8 b0 = *reinterpret_cast<const bf16x8*>(bsp0 + ((klocal + lk) ^ rx));
        bf16x8 b1 = *reinterpret_cast<const bf16x8*>(bsp1 + ((klocal + lk) ^ rx));
        acc00 = __builtin_amdgcn_mfma_f32_32x32x16_bf16(a0, b0, acc00, 0, 0, 0);
        acc01 = __builtin_amdgcn_mfma_f32_32x32x16_bf16(a0, b1, acc01, 0, 0, 0);
        acc10 = __builtin_amdgcn_mfma_f32_32x32x16_bf16(a1, b0, acc10, 0, 0, 0);
        acc11 = __builtin_amdgcn_mfma_f32_32x32x16_bf16(a1, b1, acc11, 0, 0, 0);
    }

    const float bc0 = bias[wn + lrow];
    const float bc1 = bias[wn + 32 + lrow];
    const int hi4 = 4 * (lane >> 5);

#define STORE_TILE(ACC, MI, NI, BB)                                            \
    {                                                                          \
        const int colg = wn + (NI) * 32 + lrow;                                \
        _Pragma("unroll")                                                      \
        for (int r = 0; r < 16; ++r) {                                         \
            int rowg = base + wm + (MI) * 32 + (r & 3) + 8 * (r >> 2) + hi4;   \
            if (rowg < N_NODES) {                                              \
                float v = ACC[r] + (BB);                                       \
                if (RELU) v = fmaxf(v, 0.0f);                                  \
                if (BF16_OUT)                                                  \
                    ((uint16_t*)outp)[(size_t)rowg * DIM + colg] =             \
                        (uint16_t)f2b_rne(v);                                  \
                else                                                           \
                    ((float*)outp)[(size_t)rowg * DIM + colg] = v;             \
            }                                                                  \
        }                                                                      \
    }
    STORE_TILE(acc00, 0, 0, bc0)
    STORE_TILE(acc01, 0, 1, bc1)
    STORE_TILE(acc10, 1, 0, bc0)
    STORE_TILE(acc11, 1, 1, bc1)
#undef STORE_TILE
}

extern "C" void kernel_launch(void* const* d_in, const int* in_sizes, int n_in,
                              void* d_out, int out_size, void* d_ws, size_t ws_size,
                              hipStream_t stream) {
    const float* x   = (const float*)d_in[0];
    const int*   ei  = (const int*)d_in[1];
    const float* W1l = (const float*)d_in[2];
    const float* W1r = (const float*)d_in[3];
    const float* b1  = (const float*)d_in[4];
    const float* W2l = (const float*)d_in[5];
    const float* W2r = (const float*)d_in[6];
    const float* b2  = (const float*)d_in[7];
    const int* src = ei;
    const int* dst = ei + NE;

    char* wsb = (char*)d_ws;
    int*      rowptr  = (int*)(wsb + ROW_B);
    int*      bhist   = (int*)(wsb + BHIST_B);
    int*      bbase   = (int*)(wsb + BBASE_B);
    int*      bcur    = (int*)(wsb + BCUR_B);
    int*      ssrc    = (int*)(wsb + SRC_B);
    uint32_t* xb32    = (uint32_t*)(wsb + XB_B);
    uint16_t* xb16    = (uint16_t*)(wsb + XB_B);
    uint32_t* hb32    = (uint32_t*)(wsb + HB_B);
    uint16_t* hb16    = (uint16_t*)(wsb + HB_B);
    uint32_t* mb32    = (uint32_t*)(wsb + MB_B);
    uint16_t* mb16    = (uint16_t*)(wsb + MB_B);
    uint16_t* w1      = (uint16_t*)(wsb + W1_B);
    uint16_t* w2      = (uint16_t*)(wsb + W2_B);
    uint32_t* bpair   = (uint32_t*)(wsb + BPAIR_B);
    float*    outf    = (float*)d_out;

    hipMemsetAsync(bhist, 0, 392 * sizeof(int), stream);

    k_bhist <<<BK_WG, 1024, 0, stream>>>(dst, bhist);
    k_bscan <<<1, 512, 0, stream>>>(bhist, bbase, bcur);
    k_bucket<<<BK_WG, 1024, 0, stream>>>(src, dst, bcur, bpair);
    k_sortb <<<NBUCKET, 256, 0, stream>>>(bbase, bpair, rowptr, ssrc);

    k_cvt_x<<<12500, 256, 0, stream>>>(x, xb32);
    k_cvt_w<<<64, 256, 0, stream>>>(W1l, W1r, W2l, W2r, w1, w2);

    const int agg_blocks = N_NODES / 4;            // one wave per node
    const int layer_blocks = (N_NODES + 127) / 128;

    // layer 1
    k_agg<<<agg_blocks, 256, 0, stream>>>(rowptr, ssrc, xb32, mb32);
    k_layer<true, true><<<layer_blocks, 256, 0, stream>>>(mb16, xb16, w1, b1, (void*)hb16);

    // layer 2
    k_agg<<<agg_blocks, 256, 0, stream>>>(rowptr, ssrc, hb32, mb32);
    k_layer<false, false><<<layer_blocks, 256, 0, stream>>>(mb16, hb16, w2, b2, (void*)outf);
}